// Round 14
// baseline (328.366 us; speedup 1.0000x reference)
//
#include <hip/hip_runtime.h>
#include <hip/hip_bf16.h>

#define DEVI __device__ __forceinline__

// ---- constants for this problem ----
// B=2, S=2048, D=2048, H=16, KV=4, HD=128, G=H/KV=4
// M = B*S = 4096; N_qkv = 5120 (4096 q+gate, 512 k, 512 v); K = 2048.

typedef __attribute__((ext_vector_type(8))) short bfrag;          // 8 bf16 = 16B (4 VGPRs)
typedef __attribute__((ext_vector_type(4))) float facc;           // 4 f32 acc
typedef __attribute__((ext_vector_type(4))) float f4v;
typedef __attribute__((ext_vector_type(4))) unsigned short us4;   // 4 bf16 = 8B

DEVI facc mfma16(bfrag a, bfrag b, facc c) {
  return __builtin_amdgcn_mfma_f32_16x16x32_bf16(a, b, c, 0, 0, 0);
}

DEVI void gl_lds16(const void* g, void* l) {
  // LDS dest must be WAVE-UNIFORM base; HW writes base + lane*16.
  __builtin_amdgcn_global_load_lds((__attribute__((address_space(1))) void*)g,
                                   (__attribute__((address_space(3))) void*)l,
                                   16, 0, 0);
}

// XOR swizzles (involutions, flip byte-addr bits 4..6 with low row bits).
DEVI int swz128(int a) { return a ^ (((a >> 7) & 7) << 4); }  // 128B-row tiles
DEVI int swz256(int a) { return a ^ (((a >> 8) & 7) << 4); }  // 256B-row tiles

DEVI unsigned short f2bu(float f) {
  __hip_bfloat16 h = __float2bfloat16(f);
  return *reinterpret_cast<unsigned short*>(&h);
}

// ---------------- fused cast f32 -> bf16 (all 5 tensors, one dispatch) ----------------
// segments (float4 units): x 2097152 | Wq 2097152 | Wk 262144 | Wv 262144 | Wo 1048576
__global__ __launch_bounds__(256) void cast_all(const float* __restrict__ x,
                                                const float* __restrict__ Wq,
                                                const float* __restrict__ Wk,
                                                const float* __restrict__ Wv,
                                                const float* __restrict__ Wo,
                                                unsigned short* __restrict__ x_bf,
                                                unsigned short* __restrict__ wqkv,
                                                unsigned short* __restrict__ wo_bf) {
  for (int i = blockIdx.x * 256 + threadIdx.x; i < 5767168; i += gridDim.x * 256) {
    const float* src; unsigned short* dst; int j;
    if (i < 2097152)      { src = x;  dst = x_bf;           j = i; }
    else if (i < 4194304) { src = Wq; dst = wqkv;           j = i - 2097152; }
    else if (i < 4456448) { src = Wk; dst = wqkv + 8388608; j = i - 4194304; }
    else if (i < 4718592) { src = Wv; dst = wqkv + 9437184; j = i - 4456448; }
    else                  { src = Wo; dst = wo_bf;          j = i - 4718592; }
    f4v v = ((const f4v*)src)[j];
    us4 o;
    o[0] = f2bu(v[0]); o[1] = f2bu(v[1]); o[2] = f2bu(v[2]); o[3] = f2bu(v[3]);
    ((us4*)dst)[j] = o;
  }
}

// ---------------- GEMM: C[M][N] = A[M][K] * B[N][K]^T (both row-major, K contig) ----
// 128x128 tile, BK=64 (one barrier pair per 64-K), 4 waves (2x2 of 64x64),
// T2 both-sides swizzle on As/Bs (128B rows), T1 XCD-chunked block swizzle.
template <typename OUT_T>
__global__ __launch_bounds__(256) void gemm_bt(const __hip_bfloat16* __restrict__ A,
                                               const __hip_bfloat16* __restrict__ Bm,
                                               OUT_T* __restrict__ C,
                                               int M, int N, int K) {
  __shared__ __attribute__((aligned(16))) __hip_bfloat16 As[128 * 64];  // 16KB
  __shared__ __attribute__((aligned(16))) __hip_bfloat16 Bs[128 * 64];  // 16KB
  // XCD-chunked bijective remap (nwg % 8 == 0 for all our launches)
  const int bid = blockIdx.y * gridDim.x + blockIdx.x;
  const int cpx = (gridDim.x * gridDim.y) >> 3;
  const int wg = (bid & 7) * cpx + (bid >> 3);
  const int n0 = (wg % gridDim.x) * 128, m0 = (wg / gridDim.x) * 128;
  const int tid = threadIdx.x, wave = tid >> 6, lane = tid & 63;
  const int lr = lane & 15, lg = lane >> 4;
  const int wr = wave >> 1, wc = wave & 1;

  facc acc[4][4];
#pragma unroll
  for (int m = 0; m < 4; ++m)
#pragma unroll
    for (int n = 0; n < 4; ++n) acc[m][n] = (facc){0.f, 0.f, 0.f, 0.f};

  const char* Ag = (const char*)A;
  const char* Bg = (const char*)Bm;
  const size_t rowb = (size_t)K * 2;

  for (int k0 = 0; k0 < K; k0 += 64) {
#pragma unroll
    for (int i = 0; i < 4; ++i) {
      const int wb = i * 4096 + wave * 1024;   // wave-uniform LDS byte base
      const int bo = wb + lane * 16;           // this lane's LDS byte slot
      const int row = bo >> 7;                 // 128B per row (64 bf16)
      const int kb = swz128(bo) & 127;         // pre-swizzled within-row offset
      gl_lds16(Ag + (size_t)(m0 + row) * rowb + (size_t)k0 * 2 + kb, (char*)As + wb);
      gl_lds16(Bg + (size_t)(n0 + row) * rowb + (size_t)k0 * 2 + kb, (char*)Bs + wb);
    }
    __syncthreads();
#pragma unroll
    for (int kk = 0; kk < 2; ++kk) {
      bfrag af[4], bf[4];
#pragma unroll
      for (int m = 0; m < 4; ++m)
        af[m] = *(const bfrag*)((const char*)As +
                    ((((wr * 64 + m * 16 + lr) << 7) + kk * 64 + lg * 16) ^ ((lr & 7) << 4)));
#pragma unroll
      for (int n = 0; n < 4; ++n)
        bf[n] = *(const bfrag*)((const char*)Bs +
                    ((((wc * 64 + n * 16 + lr) << 7) + kk * 64 + lg * 16) ^ ((lr & 7) << 4)));
#pragma unroll
      for (int m = 0; m < 4; ++m)
#pragma unroll
        for (int n = 0; n < 4; ++n) acc[m][n] = mfma16(af[m], bf[n], acc[m][n]);
    }
    __syncthreads();
  }

#pragma unroll
  for (int m = 0; m < 4; ++m)
#pragma unroll
    for (int n = 0; n < 4; ++n)
#pragma unroll
      for (int r = 0; r < 4; ++r) {
        const int row = m0 + wr * 64 + m * 16 + lg * 4 + r;  // verified C/D layout
        const int col = n0 + wc * 64 + n * 16 + lr;
        float v = acc[m][n][r];
        if constexpr (sizeof(OUT_T) == 4) C[(size_t)row * N + col] = v;
        else                              C[(size_t)row * N + col] = __float2bfloat16(v);
      }
}

// ---------------- q-head RMSNorm + RoPE ----------------
// One wave per (b,s,h). lane holds the rope pair (d=lane, d=lane+64).
__global__ __launch_bounds__(256) void qnorm_rope(const __hip_bfloat16* __restrict__ qkv,
                                                  const float* __restrict__ w,
                                                  const float* __restrict__ fc,
                                                  __hip_bfloat16* __restrict__ Qb) {
  int item = blockIdx.x * 4 + (threadIdx.x >> 6);  // (b*S+s)*H + h
  int lane = threadIdx.x & 63;
  int h = item & 15, bs = item >> 4, s = bs & 2047, b = bs >> 11;
  size_t base = (size_t)bs * 5120 + h * 256;
  float e1 = __bfloat162float(qkv[base + lane]);
  float e2 = __bfloat162float(qkv[base + 64 + lane]);
  float ss = e1 * e1 + e2 * e2;
#pragma unroll
  for (int d = 1; d < 64; d <<= 1) ss += __shfl_xor(ss, d);
  float rr = rsqrtf(ss * (1.0f / 128.0f) + 1e-6f);
  float n1 = e1 * rr * (1.0f + w[lane]);
  float n2 = e2 * rr * (1.0f + w[lane + 64]);
  float cs = fc[s * 128 + lane], sn = fc[s * 128 + 64 + lane];
  size_t ob = ((size_t)((b * 16 + h) * 2048) + s) * 128;
  Qb[ob + lane]      = __float2bfloat16(n1 * cs - n2 * sn);
  Qb[ob + 64 + lane] = __float2bfloat16(n2 * cs + n1 * sn);
}

// ---------------- k-head RMSNorm + RoPE ----------------
__global__ __launch_bounds__(256) void knorm_rope(const __hip_bfloat16* __restrict__ qkv,
                                                  const float* __restrict__ w,
                                                  const float* __restrict__ fc,
                                                  __hip_bfloat16* __restrict__ Kb) {
  int item = blockIdx.x * 4 + (threadIdx.x >> 6);  // (b*S+s)*KV + kv
  int lane = threadIdx.x & 63;
  int kv = item & 3, bs = item >> 2, s = bs & 2047, b = bs >> 11;
  size_t base = (size_t)bs * 5120 + 4096 + kv * 128;
  float e1 = __bfloat162float(qkv[base + lane]);
  float e2 = __bfloat162float(qkv[base + 64 + lane]);
  float ss = e1 * e1 + e2 * e2;
#pragma unroll
  for (int d = 1; d < 64; d <<= 1) ss += __shfl_xor(ss, d);
  float rr = rsqrtf(ss * (1.0f / 128.0f) + 1e-6f);
  float n1 = e1 * rr * (1.0f + w[lane]);
  float n2 = e2 * rr * (1.0f + w[lane + 64]);
  float cs = fc[s * 128 + lane], sn = fc[s * 128 + 64 + lane];
  size_t ob = ((size_t)((b * 4 + kv) * 2048) + s) * 128;
  Kb[ob + lane]      = __float2bfloat16(n1 * cs - n2 * sn);
  Kb[ob + 64 + lane] = __float2bfloat16(n2 * cs + n1 * sn);
}

// ---------------- V transpose: qkv_raw v-slice -> Vt[b][kv][d][s] ----------------
__global__ __launch_bounds__(256) void vtrans(const __hip_bfloat16* __restrict__ qkv,
                                              __hip_bfloat16* __restrict__ vt) {
  __shared__ __hip_bfloat16 tile[64][65];
  int s0 = blockIdx.x * 64, d0 = blockIdx.y * 64, bk = blockIdx.z;  // bk = b*KV+kv
  int b = bk >> 2, kv = bk & 3;
  int tid = threadIdx.x;
#pragma unroll
  for (int i = 0; i < 16; ++i) {
    int e = i * 256 + tid;
    int r = e >> 6, c = e & 63;  // r = s-idx, c = d-idx
    tile[r][c] = qkv[(size_t)(b * 2048 + s0 + r) * 5120 + 4608 + kv * 128 + d0 + c];
  }
  __syncthreads();
#pragma unroll
  for (int i = 0; i < 16; ++i) {
    int e = i * 256 + tid;
    int r = e >> 6, c = e & 63;  // r = d-idx, c = s-idx
    vt[(size_t)(bk * 128 + d0 + r) * 2048 + s0 + c] = tile[c][r];
  }
}

// ---------------- causal GQA flash attention + sigmoid gate ----------------
// 512 blocks (1-D), 256 threads. QBLK=128: each wave owns 32 q-rows as two
// 16-row subtiles s=0,1 (rows qt2*128 + s*64 + wave*16 ..+16). kf/vb LDS reads
// SHARED across subtiles -> 2x MFMA per staged tile, ~same DS traffic.
// Balance: CU c hosts {n=c, n=c+256} with qt2 = {q, 15-q} (sum const).
// SWAPPED QK^T (in-register softmax, q = lane&15); T2 swizzle; T5 setprio.
// Causal via uniform global compare (s=0's one inactive tile self-masks: p=0).
__global__ __launch_bounds__(256) void flash_attn(const __hip_bfloat16* __restrict__ Qb,
                                                  const __hip_bfloat16* __restrict__ Kb,
                                                  const __hip_bfloat16* __restrict__ Vt,
                                                  const __hip_bfloat16* __restrict__ qkv,
                                                  __hip_bfloat16* __restrict__ attn_g) {
  const int n_id = blockIdx.x;
  const int k = n_id >> 8, r = n_id & 255;
  const int qt2 = (k & 1) ? (15 - (r & 15)) : (r & 15);
  const int hb = (r >> 4) + (k << 4);       // 0..31 ; b == k
  const int h = hb & 15, b = hb >> 4;
  const int kvh = h >> 2;
  const int tid = threadIdx.x, wave = tid >> 6, lane = tid & 63;
  const int lr = lane & 15, lg = lane >> 4;

  __shared__ __attribute__((aligned(16))) __hip_bfloat16 Ks[64 * 128];      // swz256
  __shared__ __attribute__((aligned(16))) __hip_bfloat16 Vs[128 * 64];      // swz128
  __shared__ __attribute__((aligned(16))) __hip_bfloat16 Ps[2][4][16 * 64]; // per-s, per-wave

  bfrag qf[2][4];
#pragma unroll
  for (int s = 0; s < 2; ++s) {
    const __hip_bfloat16* Qp =
        Qb + ((size_t)((b * 16 + h) * 2048) + qt2 * 128 + s * 64 + wave * 16 + lr) * 128;
#pragma unroll
    for (int kk = 0; kk < 4; ++kk) qf[s][kk] = *(const bfrag*)(Qp + kk * 32 + lg * 8);
  }

  facc o[2][8];
#pragma unroll
  for (int s = 0; s < 2; ++s)
#pragma unroll
    for (int i = 0; i < 8; ++i) o[s][i] = (facc){0.f, 0.f, 0.f, 0.f};
  float m_s[2] = {-INFINITY, -INFINITY};
  float l_s[2] = {0.f, 0.f};
  const float sc = 0.08838834764831845f;  // 1/sqrt(128)

  const char* Kg0 = (const char*)(Kb + (size_t)((b * 4 + kvh) * 2048) * 128);
  const char* Vg0 = (const char*)(Vt + (size_t)((b * 4 + kvh) * 128) * 2048);

  const int T = 2 * qt2 + 2;
  for (int t = 0; t < T; ++t) {
    // stage K tile (64x128) and Vt tile, pre-swizzled GLOBAL source.
#pragma unroll
    for (int i = 0; i < 4; ++i) {
      const int wb = i * 4096 + wave * 1024;
      const int bo = wb + lane * 16;
      gl_lds16(Kg0 + (size_t)t * 16384 + swz256(bo), (char*)Ks + wb);
      const int sa = swz128(bo);
      gl_lds16(Vg0 + (size_t)(bo >> 7) * 4096 + (size_t)t * 128 + (sa & 127),
               (char*)Vs + wb);
    }
    __syncthreads();

    // QK^T for both subtiles, sharing kf reads
    facc st[2][4];
    __builtin_amdgcn_s_setprio(1);
#pragma unroll
    for (int n = 0; n < 4; ++n) {
      facc a0 = (facc){0.f, 0.f, 0.f, 0.f};
      facc a1 = (facc){0.f, 0.f, 0.f, 0.f};
#pragma unroll
      for (int kk = 0; kk < 4; ++kk) {
        bfrag kf = *(const bfrag*)((const char*)Ks +
                       (((n * 16 + lr) * 256 + kk * 64 + lg * 16) ^ ((lr & 7) << 4)));
        a0 = mfma16(kf, qf[0][kk], a0);
        a1 = mfma16(kf, qf[1][kk], a1);
      }
      st[0][n] = a0; st[1][n] = a1;
    }
    __builtin_amdgcn_s_setprio(0);

    // softmax per subtile (stat layout: lane holds q-row = lr)
#pragma unroll
    for (int s = 0; s < 2; ++s) {
      const int q_rel = qt2 * 128 + s * 64 + wave * 16 + lr - t * 64;  // mask idx > q_rel
      float pm = -INFINITY;
#pragma unroll
      for (int n = 0; n < 4; ++n)
#pragma unroll
        for (int r2 = 0; r2 < 4; ++r2) {
          float v = st[s][n][r2] * sc;
          if (n * 16 + lg * 4 + r2 > q_rel) v = -INFINITY;
          st[s][n][r2] = v;
          pm = fmaxf(pm, v);
        }
      pm = fmaxf(pm, __shfl_xor(pm, 16));
      pm = fmaxf(pm, __shfl_xor(pm, 32));

      float mn = fmaxf(m_s[s], pm);
      float alpha = __expf(m_s[s] - mn);
      m_s[s] = mn;

      float lsum = 0.f;
      us4 pw[4];
#pragma unroll
      for (int n = 0; n < 4; ++n)
#pragma unroll
        for (int r2 = 0; r2 < 4; ++r2) {
          float p = __expf(st[s][n][r2] - mn);
          lsum += p;
          pw[n][r2] = f2bu(p);
        }
      lsum += __shfl_xor(lsum, 16);
      lsum += __shfl_xor(lsum, 32);
      l_s[s] = l_s[s] * alpha + lsum;

      char* PsW = (char*)&Ps[s][0][0] + wave * 2048;
#pragma unroll
      for (int n = 0; n < 4; ++n) {
        const int byte = lr * 128 + n * 32 + lg * 8;
        *(us4*)(PsW + (byte ^ ((lr & 7) << 4))) = pw[n];
      }

      float aa[4];
#pragma unroll
      for (int r2 = 0; r2 < 4; ++r2) aa[r2] = __shfl(alpha, lg * 4 + r2);
#pragma unroll
      for (int nn = 0; nn < 8; ++nn)
#pragma unroll
        for (int r2 = 0; r2 < 4; ++r2) o[s][nn][r2] *= aa[r2];
    }

    // PV for both subtiles, sharing vb reads (compiler inserts Ps RAW lgkmcnt)
    __builtin_amdgcn_s_setprio(1);
#pragma unroll
    for (int kk2 = 0; kk2 < 2; ++kk2) {
      const int pb = (lr * 128 + kk2 * 64 + lg * 16) ^ ((lr & 7) << 4);
      bfrag pa0 = *(const bfrag*)((const char*)&Ps[0][0][0] + wave * 2048 + pb);
      bfrag pa1 = *(const bfrag*)((const char*)&Ps[1][0][0] + wave * 2048 + pb);
#pragma unroll
      for (int nn = 0; nn < 8; ++nn) {
        bfrag vb = *(const bfrag*)((const char*)Vs +
                       (((nn * 16 + lr) * 128 + kk2 * 64 + lg * 16) ^ ((lr & 7) << 4)));
        o[0][nn] = mfma16(pa0, vb, o[0][nn]);
        o[1][nn] = mfma16(pa1, vb, o[1][nn]);
      }
    }
    __builtin_amdgcn_s_setprio(0);
    __syncthreads();  // before next tile's staging overwrites Ks/Vs
  }

  // epilogue: normalize, sigmoid-gate, store bf16 [b*S+q][h*128+d]
#pragma unroll
  for (int s = 0; s < 2; ++s) {
    float inv = 1.0f / l_s[s];          // stat layout (q = lr)
    float ia[4];
#pragma unroll
    for (int r2 = 0; r2 < 4; ++r2) ia[r2] = __shfl(inv, lg * 4 + r2);
    const int q_base = qt2 * 128 + s * 64 + wave * 16 + lg * 4;
#pragma unroll
    for (int r2 = 0; r2 < 4; ++r2) {
      int q = q_base + r2;
      const __hip_bfloat16* gp = qkv + (size_t)(b * 2048 + q) * 5120 + h * 256 + 128;
      __hip_bfloat16* op = attn_g + (size_t)(b * 2048 + q) * 2048 + h * 128;
#pragma unroll
      for (int nn = 0; nn < 8; ++nn) {
        int d = nn * 16 + lr;
        float g = __bfloat162float(gp[d]);
        float sig = 1.0f / (1.0f + __expf(-g));
        op[d] = __float2bfloat16(o[s][nn][r2] * ia[r2] * sig);
      }
    }
  }
}

// ---------------- launch ----------------
extern "C" void kernel_launch(void* const* d_in, const int* in_sizes, int n_in,
                              void* d_out, int out_size, void* d_ws, size_t ws_size,
                              hipStream_t stream) {
  (void)in_sizes; (void)n_in; (void)out_size; (void)ws_size;
  const float* x  = (const float*)d_in[0];
  const float* fc = (const float*)d_in[1];
  const float* Wq = (const float*)d_in[2];
  const float* Wk = (const float*)d_in[3];
  const float* Wv = (const float*)d_in[4];
  const float* Wo = (const float*)d_in[5];
  const float* qw = (const float*)d_in[6];
  const float* kw = (const float*)d_in[7];
  float* out = (float*)d_out;
  char* ws = (char*)d_ws;

  // workspace layout (bytes), total 92,274,688
  auto* x_bf   = (__hip_bfloat16*)(ws + 0);          // 16,777,216  [4096][2048]
  auto* wqkv   = (__hip_bfloat16*)(ws + 16777216);   // 20,971,520  [5120][2048]
  auto* wo_bf  = (__hip_bfloat16*)(ws + 37748736);   //  8,388,608  [2048][2048]
  auto* qkvraw = (__hip_bfloat16*)(ws + 46137344);   // 41,943,040  [4096][5120]
  auto* vt     = (__hip_bfloat16*)(ws + 88080384);   //  4,194,304  [b][kv][128][2048]
  auto* attn_g = x_bf;                               // alias: x_bf dead after QKV GEMM
  auto* Qb     = wqkv;                               // alias: weights dead after GEMM
  auto* Kb     = (__hip_bfloat16*)(ws + 33554432);   //  4,194,304 (tail of wqkv region)

  // fused cast of all five f32 tensors to bf16 (one dispatch)
  cast_all<<<2048, 256, 0, stream>>>(x, Wq, Wk, Wv, Wo,
                                     (unsigned short*)x_bf,
                                     (unsigned short*)wqkv,
                                     (unsigned short*)wo_bf);

  // QKV projection: [4096][5120] = x_bf @ wqkv^T
  gemm_bt<__hip_bfloat16><<<dim3(40, 32), 256, 0, stream>>>(x_bf, wqkv, qkvraw, 4096, 5120, 2048);

  qnorm_rope<<<16384, 256, 0, stream>>>(qkvraw, qw, fc, Qb);
  knorm_rope<<<4096, 256, 0, stream>>>(qkvraw, kw, fc, Kb);
  vtrans<<<dim3(32, 2, 8), 256, 0, stream>>>(qkvraw, vt);

  flash_attn<<<512, 256, 0, stream>>>(Qb, Kb, vt, qkvraw, attn_g);

  // output projection: d_out[4096][2048] = attn_g @ wo_bf^T (f32 out)
  gemm_bt<float><<<dim3(16, 32), 256, 0, stream>>>(attn_g, wo_bf, out, 4096, 2048, 2048);
}

// Round 15
// 307.444 us; speedup vs baseline: 1.0681x; 1.0681x over previous
//
#include <hip/hip_runtime.h>
#include <hip/hip_bf16.h>

#define DEVI __device__ __forceinline__

// ---- constants for this problem ----
// B=2, S=2048, D=2048, H=16, KV=4, HD=128, G=H/KV=4
// M = B*S = 4096; N_qkv = 5120 (4096 q+gate, 512 k, 512 v); K = 2048.

typedef __attribute__((ext_vector_type(8))) short bfrag;          // 8 bf16 = 16B (4 VGPRs)
typedef __attribute__((ext_vector_type(4))) float facc;           // 4 f32 acc
typedef __attribute__((ext_vector_type(4))) float f4v;
typedef __attribute__((ext_vector_type(4))) unsigned short us4;   // 4 bf16 = 8B

DEVI facc mfma16(bfrag a, bfrag b, facc c) {
  return __builtin_amdgcn_mfma_f32_16x16x32_bf16(a, b, c, 0, 0, 0);
}

DEVI void gl_lds16(const void* g, void* l) {
  // LDS dest must be WAVE-UNIFORM base; HW writes base + lane*16.
  __builtin_amdgcn_global_load_lds((__attribute__((address_space(1))) void*)g,
                                   (__attribute__((address_space(3))) void*)l,
                                   16, 0, 0);
}

// XOR swizzles (involutions, flip byte-addr bits 4..6 with low row bits).
DEVI int swz128(int a) { return a ^ (((a >> 7) & 7) << 4); }  // 128B-row tiles
DEVI int swz256(int a) { return a ^ (((a >> 8) & 7) << 4); }  // 256B-row tiles

DEVI unsigned short f2bu(float f) {
  __hip_bfloat16 h = __float2bfloat16(f);
  return *reinterpret_cast<unsigned short*>(&h);
}

// ---------------- fused cast f32 -> bf16 (all 5 tensors, one dispatch) ----------------
// segments (float4 units): x 2097152 | Wq 2097152 | Wk 262144 | Wv 262144 | Wo 1048576
__global__ __launch_bounds__(256) void cast_all(const float* __restrict__ x,
                                                const float* __restrict__ Wq,
                                                const float* __restrict__ Wk,
                                                const float* __restrict__ Wv,
                                                const float* __restrict__ Wo,
                                                unsigned short* __restrict__ x_bf,
                                                unsigned short* __restrict__ wqkv,
                                                unsigned short* __restrict__ wo_bf) {
  for (int i = blockIdx.x * 256 + threadIdx.x; i < 5767168; i += gridDim.x * 256) {
    const float* src; unsigned short* dst; int j;
    if (i < 2097152)      { src = x;  dst = x_bf;           j = i; }
    else if (i < 4194304) { src = Wq; dst = wqkv;           j = i - 2097152; }
    else if (i < 4456448) { src = Wk; dst = wqkv + 8388608; j = i - 4194304; }
    else if (i < 4718592) { src = Wv; dst = wqkv + 9437184; j = i - 4456448; }
    else                  { src = Wo; dst = wo_bf;          j = i - 4718592; }
    f4v v = ((const f4v*)src)[j];
    us4 o;
    o[0] = f2bu(v[0]); o[1] = f2bu(v[1]); o[2] = f2bu(v[2]); o[3] = f2bu(v[3]);
    ((us4*)dst)[j] = o;
  }
}

// ---------------- GEMM: C[M][N] = A[M][K] * B[N][K]^T (both row-major, K contig) ----
// 128x128 tile, BK=64 (one barrier pair per 64-K), 4 waves (2x2 of 64x64),
// T2 both-sides swizzle on As/Bs (128B rows), T1 XCD-chunked block swizzle.
template <typename OUT_T>
__global__ __launch_bounds__(256) void gemm_bt(const __hip_bfloat16* __restrict__ A,
                                               const __hip_bfloat16* __restrict__ Bm,
                                               OUT_T* __restrict__ C,
                                               int M, int N, int K) {
  __shared__ __attribute__((aligned(16))) __hip_bfloat16 As[128 * 64];  // 16KB
  __shared__ __attribute__((aligned(16))) __hip_bfloat16 Bs[128 * 64];  // 16KB
  // XCD-chunked bijective remap (nwg % 8 == 0 for all our launches)
  const int bid = blockIdx.y * gridDim.x + blockIdx.x;
  const int cpx = (gridDim.x * gridDim.y) >> 3;
  const int wg = (bid & 7) * cpx + (bid >> 3);
  const int n0 = (wg % gridDim.x) * 128, m0 = (wg / gridDim.x) * 128;
  const int tid = threadIdx.x, wave = tid >> 6, lane = tid & 63;
  const int lr = lane & 15, lg = lane >> 4;
  const int wr = wave >> 1, wc = wave & 1;

  facc acc[4][4];
#pragma unroll
  for (int m = 0; m < 4; ++m)
#pragma unroll
    for (int n = 0; n < 4; ++n) acc[m][n] = (facc){0.f, 0.f, 0.f, 0.f};

  const char* Ag = (const char*)A;
  const char* Bg = (const char*)Bm;
  const size_t rowb = (size_t)K * 2;

  for (int k0 = 0; k0 < K; k0 += 64) {
#pragma unroll
    for (int i = 0; i < 4; ++i) {
      const int wb = i * 4096 + wave * 1024;   // wave-uniform LDS byte base
      const int bo = wb + lane * 16;           // this lane's LDS byte slot
      const int row = bo >> 7;                 // 128B per row (64 bf16)
      const int kb = swz128(bo) & 127;         // pre-swizzled within-row offset
      gl_lds16(Ag + (size_t)(m0 + row) * rowb + (size_t)k0 * 2 + kb, (char*)As + wb);
      gl_lds16(Bg + (size_t)(n0 + row) * rowb + (size_t)k0 * 2 + kb, (char*)Bs + wb);
    }
    __syncthreads();
#pragma unroll
    for (int kk = 0; kk < 2; ++kk) {
      bfrag af[4], bf[4];
#pragma unroll
      for (int m = 0; m < 4; ++m)
        af[m] = *(const bfrag*)((const char*)As +
                    ((((wr * 64 + m * 16 + lr) << 7) + kk * 64 + lg * 16) ^ ((lr & 7) << 4)));
#pragma unroll
      for (int n = 0; n < 4; ++n)
        bf[n] = *(const bfrag*)((const char*)Bs +
                    ((((wc * 64 + n * 16 + lr) << 7) + kk * 64 + lg * 16) ^ ((lr & 7) << 4)));
#pragma unroll
      for (int m = 0; m < 4; ++m)
#pragma unroll
        for (int n = 0; n < 4; ++n) acc[m][n] = mfma16(af[m], bf[n], acc[m][n]);
    }
    __syncthreads();
  }

#pragma unroll
  for (int m = 0; m < 4; ++m)
#pragma unroll
    for (int n = 0; n < 4; ++n)
#pragma unroll
      for (int r = 0; r < 4; ++r) {
        const int row = m0 + wr * 64 + m * 16 + lg * 4 + r;  // verified C/D layout
        const int col = n0 + wc * 64 + n * 16 + lr;
        float v = acc[m][n][r];
        if constexpr (sizeof(OUT_T) == 4) C[(size_t)row * N + col] = v;
        else                              C[(size_t)row * N + col] = __float2bfloat16(v);
      }
}

// ---------------- q-head RMSNorm + RoPE ----------------
// One wave per (b,s,h). lane holds the rope pair (d=lane, d=lane+64).
__global__ __launch_bounds__(256) void qnorm_rope(const __hip_bfloat16* __restrict__ qkv,
                                                  const float* __restrict__ w,
                                                  const float* __restrict__ fc,
                                                  __hip_bfloat16* __restrict__ Qb) {
  int item = blockIdx.x * 4 + (threadIdx.x >> 6);  // (b*S+s)*H + h
  int lane = threadIdx.x & 63;
  int h = item & 15, bs = item >> 4, s = bs & 2047, b = bs >> 11;
  size_t base = (size_t)bs * 5120 + h * 256;
  float e1 = __bfloat162float(qkv[base + lane]);
  float e2 = __bfloat162float(qkv[base + 64 + lane]);
  float ss = e1 * e1 + e2 * e2;
#pragma unroll
  for (int d = 1; d < 64; d <<= 1) ss += __shfl_xor(ss, d);
  float rr = rsqrtf(ss * (1.0f / 128.0f) + 1e-6f);
  float n1 = e1 * rr * (1.0f + w[lane]);
  float n2 = e2 * rr * (1.0f + w[lane + 64]);
  float cs = fc[s * 128 + lane], sn = fc[s * 128 + 64 + lane];
  size_t ob = ((size_t)((b * 16 + h) * 2048) + s) * 128;
  Qb[ob + lane]      = __float2bfloat16(n1 * cs - n2 * sn);
  Qb[ob + 64 + lane] = __float2bfloat16(n2 * cs + n1 * sn);
}

// ---------------- k-head RMSNorm + RoPE ----------------
__global__ __launch_bounds__(256) void knorm_rope(const __hip_bfloat16* __restrict__ qkv,
                                                  const float* __restrict__ w,
                                                  const float* __restrict__ fc,
                                                  __hip_bfloat16* __restrict__ Kb) {
  int item = blockIdx.x * 4 + (threadIdx.x >> 6);  // (b*S+s)*KV + kv
  int lane = threadIdx.x & 63;
  int kv = item & 3, bs = item >> 2, s = bs & 2047, b = bs >> 11;
  size_t base = (size_t)bs * 5120 + 4096 + kv * 128;
  float e1 = __bfloat162float(qkv[base + lane]);
  float e2 = __bfloat162float(qkv[base + 64 + lane]);
  float ss = e1 * e1 + e2 * e2;
#pragma unroll
  for (int d = 1; d < 64; d <<= 1) ss += __shfl_xor(ss, d);
  float rr = rsqrtf(ss * (1.0f / 128.0f) + 1e-6f);
  float n1 = e1 * rr * (1.0f + w[lane]);
  float n2 = e2 * rr * (1.0f + w[lane + 64]);
  float cs = fc[s * 128 + lane], sn = fc[s * 128 + 64 + lane];
  size_t ob = ((size_t)((b * 4 + kv) * 2048) + s) * 128;
  Kb[ob + lane]      = __float2bfloat16(n1 * cs - n2 * sn);
  Kb[ob + 64 + lane] = __float2bfloat16(n2 * cs + n1 * sn);
}

// ---------------- V transpose: qkv_raw v-slice -> Vt[b][kv][d][s] ----------------
__global__ __launch_bounds__(256) void vtrans(const __hip_bfloat16* __restrict__ qkv,
                                              __hip_bfloat16* __restrict__ vt) {
  __shared__ __hip_bfloat16 tile[64][65];
  int s0 = blockIdx.x * 64, d0 = blockIdx.y * 64, bk = blockIdx.z;  // bk = b*KV+kv
  int b = bk >> 2, kv = bk & 3;
  int tid = threadIdx.x;
#pragma unroll
  for (int i = 0; i < 16; ++i) {
    int e = i * 256 + tid;
    int r = e >> 6, c = e & 63;  // r = s-idx, c = d-idx
    tile[r][c] = qkv[(size_t)(b * 2048 + s0 + r) * 5120 + 4608 + kv * 128 + d0 + c];
  }
  __syncthreads();
#pragma unroll
  for (int i = 0; i < 16; ++i) {
    int e = i * 256 + tid;
    int r = e >> 6, c = e & 63;  // r = d-idx, c = s-idx
    vt[(size_t)(bk * 128 + d0 + r) * 2048 + s0 + c] = tile[c][r];
  }
}

// ---------------- causal GQA flash attention + sigmoid gate ----------------
// 512 blocks (1-D), 512 threads = 8 waves. QBLK=128: wave w owns the 16 q-rows
// [qt2*128 + w*16, +16) — ONE subtile per wave (r12 per-wave state, VGPR ~96),
// but 8 waves SHARE each staged K/V tile: tile-stages halve at constant 16
// waves/CU (2 blocks x 8 waves). Balance: CU c hosts {n=c, n=c+256} with
// qt2 = {q, 15-q} (T-sum = 34 const). SWAPPED QK^T in-register softmax;
// T2 swizzle (gl_lds + pre-swizzled global source); T5 setprio.
__global__ __launch_bounds__(512) void flash_attn(const __hip_bfloat16* __restrict__ Qb,
                                                  const __hip_bfloat16* __restrict__ Kb,
                                                  const __hip_bfloat16* __restrict__ Vt,
                                                  const __hip_bfloat16* __restrict__ qkv,
                                                  __hip_bfloat16* __restrict__ attn_g) {
  const int n_id = blockIdx.x;
  const int k = n_id >> 8, r = n_id & 255;
  const int qt2 = (k & 1) ? (15 - (r & 15)) : (r & 15);
  const int hb = (r >> 4) + (k << 4);       // 0..31 ; b == k
  const int h = hb & 15, b = hb >> 4;
  const int kvh = h >> 2;
  const int tid = threadIdx.x, wave = tid >> 6, lane = tid & 63;
  const int lr = lane & 15, lg = lane >> 4;

  __shared__ __attribute__((aligned(16))) __hip_bfloat16 Ks[64 * 128];   // swz256
  __shared__ __attribute__((aligned(16))) __hip_bfloat16 Vs[128 * 64];   // swz128
  __shared__ __attribute__((aligned(16))) __hip_bfloat16 Ps[8][16 * 64]; // per-wave

  bfrag qf[4];
  {
    const __hip_bfloat16* Qp =
        Qb + ((size_t)((b * 16 + h) * 2048) + qt2 * 128 + wave * 16 + lr) * 128;
#pragma unroll
    for (int kk = 0; kk < 4; ++kk) qf[kk] = *(const bfrag*)(Qp + kk * 32 + lg * 8);
  }

  facc o[8];
#pragma unroll
  for (int i = 0; i < 8; ++i) o[i] = (facc){0.f, 0.f, 0.f, 0.f};
  float m_s = -INFINITY;  // running max for q-row (lane&15)
  float l_s = 0.f;        // running denom for q-row (lane&15)
  const float sc = 0.08838834764831845f;  // 1/sqrt(128)

  const char* Kg0 = (const char*)(Kb + (size_t)((b * 4 + kvh) * 2048) * 128);
  const char* Vg0 = (const char*)(Vt + (size_t)((b * 4 + kvh) * 128) * 2048);
  char* PsW = (char*)&Ps[0][0] + wave * 2048;

  const int T = 2 * qt2 + 2;
  for (int t = 0; t < T; ++t) {
    // stage K tile (64x128, 16KB) + Vt tile across 8 waves (2 segs/wave),
    // pre-swizzling the GLOBAL source so swizzled reads see correct data.
#pragma unroll
    for (int i = 0; i < 2; ++i) {
      const int wb = i * 8192 + wave * 1024;
      const int bo = wb + lane * 16;
      gl_lds16(Kg0 + (size_t)t * 16384 + swz256(bo), (char*)Ks + wb);
      const int sa = swz128(bo);
      gl_lds16(Vg0 + (size_t)(bo >> 7) * 4096 + (size_t)t * 128 + (sa & 127),
               (char*)Vs + wb);
    }
    __syncthreads();

    // scores (swapped): st[n][r2] = S[kv = n*16+lg*4+r2][q = lr]
    facc st[4];
    __builtin_amdgcn_s_setprio(1);
#pragma unroll
    for (int n = 0; n < 4; ++n) {
      facc a = (facc){0.f, 0.f, 0.f, 0.f};
#pragma unroll
      for (int kk = 0; kk < 4; ++kk) {
        bfrag kf = *(const bfrag*)((const char*)Ks +
                       (((n * 16 + lr) * 256 + kk * 64 + lg * 16) ^ ((lr & 7) << 4)));
        a = mfma16(kf, qf[kk], a);   // SWAPPED: K as A, Q as B
      }
      st[n] = a;
    }
    __builtin_amdgcn_s_setprio(0);

    const int q_rel = qt2 * 128 + wave * 16 + lr - t * 64;  // mask idx > q_rel
    float pm = -INFINITY;
#pragma unroll
    for (int n = 0; n < 4; ++n)
#pragma unroll
      for (int r2 = 0; r2 < 4; ++r2) {
        float v = st[n][r2] * sc;
        if (n * 16 + lg * 4 + r2 > q_rel) v = -INFINITY;
        st[n][r2] = v;
        pm = fmaxf(pm, v);
      }
    // cross-lane max over the 4 lanes holding this q-row (lg direction)
    pm = fmaxf(pm, __shfl_xor(pm, 16));
    pm = fmaxf(pm, __shfl_xor(pm, 32));

    float mn = fmaxf(m_s, pm);
    float alpha = __expf(m_s - mn);
    m_s = mn;

    float lsum = 0.f;
    us4 pw[4];
#pragma unroll
    for (int n = 0; n < 4; ++n)
#pragma unroll
      for (int r2 = 0; r2 < 4; ++r2) {
        float p = __expf(st[n][r2] - m_s);
        lsum += p;
        pw[n][r2] = f2bu(p);
      }
    lsum += __shfl_xor(lsum, 16);
    lsum += __shfl_xor(lsum, 32);
    l_s = l_s * alpha + lsum;

    // P write: 4 consecutive kv per lane per n-tile -> ds_write_b64
#pragma unroll
    for (int n = 0; n < 4; ++n) {
      const int byte = lr * 128 + n * 32 + lg * 8;
      *(us4*)(PsW + (byte ^ ((lr & 7) << 4))) = pw[n];
    }

    // rescale O (acc layout rows q = lg*4+r2): fetch alpha from stat layout
    float alpha_acc[4];
#pragma unroll
    for (int r2 = 0; r2 < 4; ++r2) alpha_acc[r2] = __shfl(alpha, lg * 4 + r2);
#pragma unroll
    for (int nn = 0; nn < 8; ++nn)
#pragma unroll
      for (int r2 = 0; r2 < 4; ++r2) o[nn][r2] *= alpha_acc[r2];

    // O += P (16x64) @ V (64x128)   (compiler inserts the Ps RAW lgkmcnt)
    __builtin_amdgcn_s_setprio(1);
#pragma unroll
    for (int kk2 = 0; kk2 < 2; ++kk2) {
      bfrag pa = *(const bfrag*)((const char*)PsW +
                     ((lr * 128 + kk2 * 64 + lg * 16) ^ ((lr & 7) << 4)));
#pragma unroll
      for (int nn = 0; nn < 8; ++nn) {
        bfrag vb = *(const bfrag*)((const char*)Vs +
                       (((nn * 16 + lr) * 128 + kk2 * 64 + lg * 16) ^ ((lr & 7) << 4)));
        o[nn] = mfma16(pa, vb, o[nn]);
      }
    }
    __builtin_amdgcn_s_setprio(0);
    __syncthreads();  // before next tile's staging overwrites Ks/Vs
  }

  // epilogue: normalize, sigmoid-gate, store bf16 [b*S+q][h*128+d]
  float inv = 1.0f / l_s;             // stat layout (q = lr)
  float inv_acc[4];
#pragma unroll
  for (int r2 = 0; r2 < 4; ++r2) inv_acc[r2] = __shfl(inv, lg * 4 + r2);
  const int q_base = qt2 * 128 + wave * 16 + lg * 4;
#pragma unroll
  for (int r2 = 0; r2 < 4; ++r2) {
    int q = q_base + r2;
    const __hip_bfloat16* gp = qkv + (size_t)(b * 2048 + q) * 5120 + h * 256 + 128;
    __hip_bfloat16* op = attn_g + (size_t)(b * 2048 + q) * 2048 + h * 128;
#pragma unroll
    for (int nn = 0; nn < 8; ++nn) {
      int d = nn * 16 + lr;
      float g = __bfloat162float(gp[d]);
      float sig = 1.0f / (1.0f + __expf(-g));
      op[d] = __float2bfloat16(o[nn][r2] * inv_acc[r2] * sig);
    }
  }
}

// ---------------- launch ----------------
extern "C" void kernel_launch(void* const* d_in, const int* in_sizes, int n_in,
                              void* d_out, int out_size, void* d_ws, size_t ws_size,
                              hipStream_t stream) {
  (void)in_sizes; (void)n_in; (void)out_size; (void)ws_size;
  const float* x  = (const float*)d_in[0];
  const float* fc = (const float*)d_in[1];
  const float* Wq = (const float*)d_in[2];
  const float* Wk = (const float*)d_in[3];
  const float* Wv = (const float*)d_in[4];
  const float* Wo = (const float*)d_in[5];
  const float* qw = (const float*)d_in[6];
  const float* kw = (const float*)d_in[7];
  float* out = (float*)d_out;
  char* ws = (char*)d_ws;

  // workspace layout (bytes), total 92,274,688
  auto* x_bf   = (__hip_bfloat16*)(ws + 0);          // 16,777,216  [4096][2048]
  auto* wqkv   = (__hip_bfloat16*)(ws + 16777216);   // 20,971,520  [5120][2048]
  auto* wo_bf  = (__hip_bfloat16*)(ws + 37748736);   //  8,388,608  [2048][2048]
  auto* qkvraw = (__hip_bfloat16*)(ws + 46137344);   // 41,943,040  [4096][5120]
  auto* vt     = (__hip_bfloat16*)(ws + 88080384);   //  4,194,304  [b][kv][128][2048]
  auto* attn_g = x_bf;                               // alias: x_bf dead after QKV GEMM
  auto* Qb     = wqkv;                               // alias: weights dead after GEMM
  auto* Kb     = (__hip_bfloat16*)(ws + 33554432);   //  4,194,304 (tail of wqkv region)

  // fused cast of all five f32 tensors to bf16 (one dispatch)
  cast_all<<<2048, 256, 0, stream>>>(x, Wq, Wk, Wv, Wo,
                                     (unsigned short*)x_bf,
                                     (unsigned short*)wqkv,
                                     (unsigned short*)wo_bf);

  // QKV projection: [4096][5120] = x_bf @ wqkv^T
  gemm_bt<__hip_bfloat16><<<dim3(40, 32), 256, 0, stream>>>(x_bf, wqkv, qkvraw, 4096, 5120, 2048);

  qnorm_rope<<<16384, 256, 0, stream>>>(qkvraw, qw, fc, Qb);
  knorm_rope<<<4096, 256, 0, stream>>>(qkvraw, kw, fc, Kb);
  vtrans<<<dim3(32, 2, 8), 256, 0, stream>>>(qkvraw, vt);

  flash_attn<<<512, 512, 0, stream>>>(Qb, Kb, vt, qkvraw, attn_g);

  // output projection: d_out[4096][2048] = attn_g @ wo_bf^T (f32 out)
  gemm_bt<float><<<dim3(16, 32), 256, 0, stream>>>(attn_g, wo_bf, out, 4096, 2048, 2048);
}

// Round 16
// 304.239 us; speedup vs baseline: 1.0793x; 1.0105x over previous
//
#include <hip/hip_runtime.h>
#include <hip/hip_bf16.h>

#define DEVI __device__ __forceinline__

// ---- constants for this problem ----
// B=2, S=2048, D=2048, H=16, KV=4, HD=128, G=H/KV=4
// M = B*S = 4096; N_qkv = 5120 (4096 q+gate, 512 k, 512 v); K = 2048.

typedef __attribute__((ext_vector_type(8))) short bfrag;          // 8 bf16 = 16B (4 VGPRs)
typedef __attribute__((ext_vector_type(4))) float facc;           // 4 f32 acc
typedef __attribute__((ext_vector_type(4))) float f4v;
typedef __attribute__((ext_vector_type(4))) unsigned short us4;   // 4 bf16 = 8B

DEVI facc mfma16(bfrag a, bfrag b, facc c) {
  return __builtin_amdgcn_mfma_f32_16x16x32_bf16(a, b, c, 0, 0, 0);
}

DEVI void gl_lds16(const void* g, void* l) {
  // LDS dest must be WAVE-UNIFORM base; HW writes base + lane*16.
  __builtin_amdgcn_global_load_lds((__attribute__((address_space(1))) void*)g,
                                   (__attribute__((address_space(3))) void*)l,
                                   16, 0, 0);
}

// XOR swizzles (involutions, flip byte-addr bits 4..6 with low row bits).
DEVI int swz128(int a) { return a ^ (((a >> 7) & 7) << 4); }  // 128B-row tiles
DEVI int swz256(int a) { return a ^ (((a >> 8) & 7) << 4); }  // 256B-row tiles

DEVI unsigned short f2bu(float f) {
  __hip_bfloat16 h = __float2bfloat16(f);
  return *reinterpret_cast<unsigned short*>(&h);
}

// ---------------- fused cast f32 -> bf16 (all 5 tensors, one dispatch) ----------------
// segments (float4 units): x 2097152 | Wq 2097152 | Wk 262144 | Wv 262144 | Wo 1048576
__global__ __launch_bounds__(256) void cast_all(const float* __restrict__ x,
                                                const float* __restrict__ Wq,
                                                const float* __restrict__ Wk,
                                                const float* __restrict__ Wv,
                                                const float* __restrict__ Wo,
                                                unsigned short* __restrict__ x_bf,
                                                unsigned short* __restrict__ wqkv,
                                                unsigned short* __restrict__ wo_bf) {
  for (int i = blockIdx.x * 256 + threadIdx.x; i < 5767168; i += gridDim.x * 256) {
    const float* src; unsigned short* dst; int j;
    if (i < 2097152)      { src = x;  dst = x_bf;           j = i; }
    else if (i < 4194304) { src = Wq; dst = wqkv;           j = i - 2097152; }
    else if (i < 4456448) { src = Wk; dst = wqkv + 8388608; j = i - 4194304; }
    else if (i < 4718592) { src = Wv; dst = wqkv + 9437184; j = i - 4456448; }
    else                  { src = Wo; dst = wo_bf;          j = i - 4718592; }
    f4v v = ((const f4v*)src)[j];
    us4 o;
    o[0] = f2bu(v[0]); o[1] = f2bu(v[1]); o[2] = f2bu(v[2]); o[3] = f2bu(v[3]);
    ((us4*)dst)[j] = o;
  }
}

// ---------------- GEMM: C[M][N] = A[M][K] * B[N][K]^T (both row-major, K contig) ----
// 128x128 tile, BK=64 (one barrier pair per 64-K), 4 waves (2x2 of 64x64),
// T2 both-sides swizzle on As/Bs (128B rows), T1 XCD-chunked block swizzle.
template <typename OUT_T>
__global__ __launch_bounds__(256) void gemm_bt(const __hip_bfloat16* __restrict__ A,
                                               const __hip_bfloat16* __restrict__ Bm,
                                               OUT_T* __restrict__ C,
                                               int M, int N, int K) {
  __shared__ __attribute__((aligned(16))) __hip_bfloat16 As[128 * 64];  // 16KB
  __shared__ __attribute__((aligned(16))) __hip_bfloat16 Bs[128 * 64];  // 16KB
  // XCD-chunked bijective remap (nwg % 8 == 0 for all our launches)
  const int bid = blockIdx.y * gridDim.x + blockIdx.x;
  const int cpx = (gridDim.x * gridDim.y) >> 3;
  const int wg = (bid & 7) * cpx + (bid >> 3);
  const int n0 = (wg % gridDim.x) * 128, m0 = (wg / gridDim.x) * 128;
  const int tid = threadIdx.x, wave = tid >> 6, lane = tid & 63;
  const int lr = lane & 15, lg = lane >> 4;
  const int wr = wave >> 1, wc = wave & 1;

  facc acc[4][4];
#pragma unroll
  for (int m = 0; m < 4; ++m)
#pragma unroll
    for (int n = 0; n < 4; ++n) acc[m][n] = (facc){0.f, 0.f, 0.f, 0.f};

  const char* Ag = (const char*)A;
  const char* Bg = (const char*)Bm;
  const size_t rowb = (size_t)K * 2;

  for (int k0 = 0; k0 < K; k0 += 64) {
#pragma unroll
    for (int i = 0; i < 4; ++i) {
      const int wb = i * 4096 + wave * 1024;   // wave-uniform LDS byte base
      const int bo = wb + lane * 16;           // this lane's LDS byte slot
      const int row = bo >> 7;                 // 128B per row (64 bf16)
      const int kb = swz128(bo) & 127;         // pre-swizzled within-row offset
      gl_lds16(Ag + (size_t)(m0 + row) * rowb + (size_t)k0 * 2 + kb, (char*)As + wb);
      gl_lds16(Bg + (size_t)(n0 + row) * rowb + (size_t)k0 * 2 + kb, (char*)Bs + wb);
    }
    __syncthreads();
#pragma unroll
    for (int kk = 0; kk < 2; ++kk) {
      bfrag af[4], bf[4];
#pragma unroll
      for (int m = 0; m < 4; ++m)
        af[m] = *(const bfrag*)((const char*)As +
                    ((((wr * 64 + m * 16 + lr) << 7) + kk * 64 + lg * 16) ^ ((lr & 7) << 4)));
#pragma unroll
      for (int n = 0; n < 4; ++n)
        bf[n] = *(const bfrag*)((const char*)Bs +
                    ((((wc * 64 + n * 16 + lr) << 7) + kk * 64 + lg * 16) ^ ((lr & 7) << 4)));
#pragma unroll
      for (int m = 0; m < 4; ++m)
#pragma unroll
        for (int n = 0; n < 4; ++n) acc[m][n] = mfma16(af[m], bf[n], acc[m][n]);
    }
    __syncthreads();
  }

#pragma unroll
  for (int m = 0; m < 4; ++m)
#pragma unroll
    for (int n = 0; n < 4; ++n)
#pragma unroll
      for (int r = 0; r < 4; ++r) {
        const int row = m0 + wr * 64 + m * 16 + lg * 4 + r;  // verified C/D layout
        const int col = n0 + wc * 64 + n * 16 + lr;
        float v = acc[m][n][r];
        if constexpr (sizeof(OUT_T) == 4) C[(size_t)row * N + col] = v;
        else                              C[(size_t)row * N + col] = __float2bfloat16(v);
      }
}

// ---------------- q-head RMSNorm + RoPE ----------------
// One wave per (b,s,h). lane holds the rope pair (d=lane, d=lane+64).
__global__ __launch_bounds__(256) void qnorm_rope(const __hip_bfloat16* __restrict__ qkv,
                                                  const float* __restrict__ w,
                                                  const float* __restrict__ fc,
                                                  __hip_bfloat16* __restrict__ Qb) {
  int item = blockIdx.x * 4 + (threadIdx.x >> 6);  // (b*S+s)*H + h
  int lane = threadIdx.x & 63;
  int h = item & 15, bs = item >> 4, s = bs & 2047, b = bs >> 11;
  size_t base = (size_t)bs * 5120 + h * 256;
  float e1 = __bfloat162float(qkv[base + lane]);
  float e2 = __bfloat162float(qkv[base + 64 + lane]);
  float ss = e1 * e1 + e2 * e2;
#pragma unroll
  for (int d = 1; d < 64; d <<= 1) ss += __shfl_xor(ss, d);
  float rr = rsqrtf(ss * (1.0f / 128.0f) + 1e-6f);
  float n1 = e1 * rr * (1.0f + w[lane]);
  float n2 = e2 * rr * (1.0f + w[lane + 64]);
  float cs = fc[s * 128 + lane], sn = fc[s * 128 + 64 + lane];
  size_t ob = ((size_t)((b * 16 + h) * 2048) + s) * 128;
  Qb[ob + lane]      = __float2bfloat16(n1 * cs - n2 * sn);
  Qb[ob + 64 + lane] = __float2bfloat16(n2 * cs + n1 * sn);
}

// ---------------- k-head RMSNorm + RoPE ----------------
__global__ __launch_bounds__(256) void knorm_rope(const __hip_bfloat16* __restrict__ qkv,
                                                  const float* __restrict__ w,
                                                  const float* __restrict__ fc,
                                                  __hip_bfloat16* __restrict__ Kb) {
  int item = blockIdx.x * 4 + (threadIdx.x >> 6);  // (b*S+s)*KV + kv
  int lane = threadIdx.x & 63;
  int kv = item & 3, bs = item >> 2, s = bs & 2047, b = bs >> 11;
  size_t base = (size_t)bs * 5120 + 4096 + kv * 128;
  float e1 = __bfloat162float(qkv[base + lane]);
  float e2 = __bfloat162float(qkv[base + 64 + lane]);
  float ss = e1 * e1 + e2 * e2;
#pragma unroll
  for (int d = 1; d < 64; d <<= 1) ss += __shfl_xor(ss, d);
  float rr = rsqrtf(ss * (1.0f / 128.0f) + 1e-6f);
  float n1 = e1 * rr * (1.0f + w[lane]);
  float n2 = e2 * rr * (1.0f + w[lane + 64]);
  float cs = fc[s * 128 + lane], sn = fc[s * 128 + 64 + lane];
  size_t ob = ((size_t)((b * 4 + kv) * 2048) + s) * 128;
  Kb[ob + lane]      = __float2bfloat16(n1 * cs - n2 * sn);
  Kb[ob + 64 + lane] = __float2bfloat16(n2 * cs + n1 * sn);
}

// ---------------- V transpose: qkv_raw v-slice -> Vt[b][kv][d][s] ----------------
__global__ __launch_bounds__(256) void vtrans(const __hip_bfloat16* __restrict__ qkv,
                                              __hip_bfloat16* __restrict__ vt) {
  __shared__ __hip_bfloat16 tile[64][65];
  int s0 = blockIdx.x * 64, d0 = blockIdx.y * 64, bk = blockIdx.z;  // bk = b*KV+kv
  int b = bk >> 2, kv = bk & 3;
  int tid = threadIdx.x;
#pragma unroll
  for (int i = 0; i < 16; ++i) {
    int e = i * 256 + tid;
    int r = e >> 6, c = e & 63;  // r = s-idx, c = d-idx
    tile[r][c] = qkv[(size_t)(b * 2048 + s0 + r) * 5120 + 4608 + kv * 128 + d0 + c];
  }
  __syncthreads();
#pragma unroll
  for (int i = 0; i < 16; ++i) {
    int e = i * 256 + tid;
    int r = e >> 6, c = e & 63;  // r = d-idx, c = s-idx
    vt[(size_t)(bk * 128 + d0 + r) * 2048 + s0 + c] = tile[c][r];
  }
}

// ---------------- causal GQA flash attention + sigmoid gate ----------------
// 512 blocks (1-D), 512 threads = 8 waves. QBLK=128: wave w owns the 16 q-rows
// [qt2*128 + w*16, +16); 8 waves SHARE each staged K/V tile. Balance: CU c
// hosts {n=c, n=c+256} with qt2 = {q, 15-q}. SWAPPED QK^T in-register softmax;
// T2 swizzle; T5 setprio; T13 defer-max (THR=8); wave-uniform causal-mask skip.
__global__ __launch_bounds__(512) void flash_attn(const __hip_bfloat16* __restrict__ Qb,
                                                  const __hip_bfloat16* __restrict__ Kb,
                                                  const __hip_bfloat16* __restrict__ Vt,
                                                  const __hip_bfloat16* __restrict__ qkv,
                                                  __hip_bfloat16* __restrict__ attn_g) {
  const int n_id = blockIdx.x;
  const int k = n_id >> 8, r = n_id & 255;
  const int qt2 = (k & 1) ? (15 - (r & 15)) : (r & 15);
  const int hb = (r >> 4) + (k << 4);       // 0..31 ; b == k
  const int h = hb & 15, b = hb >> 4;
  const int kvh = h >> 2;
  const int tid = threadIdx.x, wave = tid >> 6, lane = tid & 63;
  const int lr = lane & 15, lg = lane >> 4;

  __shared__ __attribute__((aligned(16))) __hip_bfloat16 Ks[64 * 128];   // swz256
  __shared__ __attribute__((aligned(16))) __hip_bfloat16 Vs[128 * 64];   // swz128
  __shared__ __attribute__((aligned(16))) __hip_bfloat16 Ps[8][16 * 64]; // per-wave

  bfrag qf[4];
  {
    const __hip_bfloat16* Qp =
        Qb + ((size_t)((b * 16 + h) * 2048) + qt2 * 128 + wave * 16 + lr) * 128;
#pragma unroll
    for (int kk = 0; kk < 4; ++kk) qf[kk] = *(const bfrag*)(Qp + kk * 32 + lg * 8);
  }

  facc o[8];
#pragma unroll
  for (int i = 0; i < 8; ++i) o[i] = (facc){0.f, 0.f, 0.f, 0.f};
  float m_s = -INFINITY;  // running max for q-row (lane&15)
  float l_s = 0.f;        // running denom for q-row (lane&15)
  const float sc = 0.08838834764831845f;  // 1/sqrt(128)

  const char* Kg0 = (const char*)(Kb + (size_t)((b * 4 + kvh) * 2048) * 128);
  const char* Vg0 = (const char*)(Vt + (size_t)((b * 4 + kvh) * 128) * 2048);
  char* PsW = (char*)&Ps[0][0] + wave * 2048;

  const int T = 2 * qt2 + 2;
  for (int t = 0; t < T; ++t) {
    // stage K tile (64x128, 16KB) + Vt tile across 8 waves (2 segs/wave),
    // pre-swizzling the GLOBAL source so swizzled reads see correct data.
#pragma unroll
    for (int i = 0; i < 2; ++i) {
      const int wb = i * 8192 + wave * 1024;
      const int bo = wb + lane * 16;
      gl_lds16(Kg0 + (size_t)t * 16384 + swz256(bo), (char*)Ks + wb);
      const int sa = swz128(bo);
      gl_lds16(Vg0 + (size_t)(bo >> 7) * 4096 + (size_t)t * 128 + (sa & 127),
               (char*)Vs + wb);
    }
    __syncthreads();

    // scores (swapped): st[n][r2] = S[kv = n*16+lg*4+r2][q = lr]
    facc st[4];
    __builtin_amdgcn_s_setprio(1);
#pragma unroll
    for (int n = 0; n < 4; ++n) {
      facc a = (facc){0.f, 0.f, 0.f, 0.f};
#pragma unroll
      for (int kk = 0; kk < 4; ++kk) {
        bfrag kf = *(const bfrag*)((const char*)Ks +
                       (((n * 16 + lr) * 256 + kk * 64 + lg * 16) ^ ((lr & 7) << 4)));
        a = mfma16(kf, qf[kk], a);   // SWAPPED: K as A, Q as B
      }
      st[n] = a;
    }
    __builtin_amdgcn_s_setprio(0);

    float pm = -INFINITY;
    if (t * 64 + 63 > qt2 * 128 + wave * 16) {   // wave-uniform: mask needed
      const int q_rel = qt2 * 128 + wave * 16 + lr - t * 64;
#pragma unroll
      for (int n = 0; n < 4; ++n)
#pragma unroll
        for (int r2 = 0; r2 < 4; ++r2) {
          float v = st[n][r2] * sc;
          if (n * 16 + lg * 4 + r2 > q_rel) v = -INFINITY;
          st[n][r2] = v;
          pm = fmaxf(pm, v);
        }
    } else {                                      // interior tile: no masking
#pragma unroll
      for (int n = 0; n < 4; ++n)
#pragma unroll
        for (int r2 = 0; r2 < 4; ++r2) {
          float v = st[n][r2] * sc;
          st[n][r2] = v;
          pm = fmaxf(pm, v);
        }
    }
    // cross-lane max over the 4 lanes holding this q-row (lg direction)
    pm = fmaxf(pm, __shfl_xor(pm, 16));
    pm = fmaxf(pm, __shfl_xor(pm, 32));

    // T13 defer-max: skip rescale when max growth <= 8 (first tile: m_s=-inf
    // makes pm - m_s = +inf -> no skip, so m_s becomes finite immediately).
    const bool skip = __all(pm <= m_s + 8.0f);
    float alpha = 1.0f;
    if (!skip) {
      float mn = fmaxf(m_s, pm);
      alpha = __expf(m_s - mn);
      m_s = mn;
    }

    float lsum = 0.f;
    us4 pw[4];
#pragma unroll
    for (int n = 0; n < 4; ++n)
#pragma unroll
      for (int r2 = 0; r2 < 4; ++r2) {
        float p = __expf(st[n][r2] - m_s);   // bounded by e^8 when deferred
        lsum += p;
        pw[n][r2] = f2bu(p);
      }
    lsum += __shfl_xor(lsum, 16);
    lsum += __shfl_xor(lsum, 32);
    l_s = l_s * alpha + lsum;

    // P write: 4 consecutive kv per lane per n-tile -> ds_write_b64
#pragma unroll
    for (int n = 0; n < 4; ++n) {
      const int byte = lr * 128 + n * 32 + lg * 8;
      *(us4*)(PsW + (byte ^ ((lr & 7) << 4))) = pw[n];
    }

    // rescale O only when max moved (acc layout rows q = lg*4+r2)
    if (!skip) {
      float alpha_acc[4];
#pragma unroll
      for (int r2 = 0; r2 < 4; ++r2) alpha_acc[r2] = __shfl(alpha, lg * 4 + r2);
#pragma unroll
      for (int nn = 0; nn < 8; ++nn)
#pragma unroll
        for (int r2 = 0; r2 < 4; ++r2) o[nn][r2] *= alpha_acc[r2];
    }

    // O += P (16x64) @ V (64x128)   (compiler inserts the Ps RAW lgkmcnt)
    __builtin_amdgcn_s_setprio(1);
#pragma unroll
    for (int kk2 = 0; kk2 < 2; ++kk2) {
      bfrag pa = *(const bfrag*)((const char*)PsW +
                     ((lr * 128 + kk2 * 64 + lg * 16) ^ ((lr & 7) << 4)));
#pragma unroll
      for (int nn = 0; nn < 8; ++nn) {
        bfrag vb = *(const bfrag*)((const char*)Vs +
                       (((nn * 16 + lr) * 128 + kk2 * 64 + lg * 16) ^ ((lr & 7) << 4)));
        o[nn] = mfma16(pa, vb, o[nn]);
      }
    }
    __builtin_amdgcn_s_setprio(0);
    __syncthreads();  // before next tile's staging overwrites Ks/Vs
  }

  // epilogue: normalize, sigmoid-gate, store bf16 [b*S+q][h*128+d]
  float inv = 1.0f / l_s;             // stat layout (q = lr)
  float inv_acc[4];
#pragma unroll
  for (int r2 = 0; r2 < 4; ++r2) inv_acc[r2] = __shfl(inv, lg * 4 + r2);
  const int q_base = qt2 * 128 + wave * 16 + lg * 4;
#pragma unroll
  for (int r2 = 0; r2 < 4; ++r2) {
    int q = q_base + r2;
    const __hip_bfloat16* gp = qkv + (size_t)(b * 2048 + q) * 5120 + h * 256 + 128;
    __hip_bfloat16* op = attn_g + (size_t)(b * 2048 + q) * 2048 + h * 128;
#pragma unroll
    for (int nn = 0; nn < 8; ++nn) {
      int d = nn * 16 + lr;
      float g = __bfloat162float(gp[d]);
      float sig = 1.0f / (1.0f + __expf(-g));
      op[d] = __float2bfloat16(o[nn][r2] * inv_acc[r2] * sig);
    }
  }
}

// ---------------- launch ----------------
extern "C" void kernel_launch(void* const* d_in, const int* in_sizes, int n_in,
                              void* d_out, int out_size, void* d_ws, size_t ws_size,
                              hipStream_t stream) {
  (void)in_sizes; (void)n_in; (void)out_size; (void)ws_size;
  const float* x  = (const float*)d_in[0];
  const float* fc = (const float*)d_in[1];
  const float* Wq = (const float*)d_in[2];
  const float* Wk = (const float*)d_in[3];
  const float* Wv = (const float*)d_in[4];
  const float* Wo = (const float*)d_in[5];
  const float* qw = (const float*)d_in[6];
  const float* kw = (const float*)d_in[7];
  float* out = (float*)d_out;
  char* ws = (char*)d_ws;

  // workspace layout (bytes), total 92,274,688
  auto* x_bf   = (__hip_bfloat16*)(ws + 0);          // 16,777,216  [4096][2048]
  auto* wqkv   = (__hip_bfloat16*)(ws + 16777216);   // 20,971,520  [5120][2048]
  auto* wo_bf  = (__hip_bfloat16*)(ws + 37748736);   //  8,388,608  [2048][2048]
  auto* qkvraw = (__hip_bfloat16*)(ws + 46137344);   // 41,943,040  [4096][5120]
  auto* vt     = (__hip_bfloat16*)(ws + 88080384);   //  4,194,304  [b][kv][128][2048]
  auto* attn_g = x_bf;                               // alias: x_bf dead after QKV GEMM
  auto* Qb     = wqkv;                               // alias: weights dead after GEMM
  auto* Kb     = (__hip_bfloat16*)(ws + 33554432);   //  4,194,304 (tail of wqkv region)

  // fused cast of all five f32 tensors to bf16 (one dispatch)
  cast_all<<<2048, 256, 0, stream>>>(x, Wq, Wk, Wv, Wo,
                                     (unsigned short*)x_bf,
                                     (unsigned short*)wqkv,
                                     (unsigned short*)wo_bf);

  // QKV projection: [4096][5120] = x_bf @ wqkv^T
  gemm_bt<__hip_bfloat16><<<dim3(40, 32), 256, 0, stream>>>(x_bf, wqkv, qkvraw, 4096, 5120, 2048);

  qnorm_rope<<<16384, 256, 0, stream>>>(qkvraw, qw, fc, Qb);
  knorm_rope<<<4096, 256, 0, stream>>>(qkvraw, kw, fc, Kb);
  vtrans<<<dim3(32, 2, 8), 256, 0, stream>>>(qkvraw, vt);

  flash_attn<<<512, 512, 0, stream>>>(Qb, Kb, vt, qkvraw, attn_g);

  // output projection: d_out[4096][2048] = attn_g @ wo_bf^T (f32 out)
  gemm_bt<float><<<dim3(16, 32), 256, 0, stream>>>(attn_g, wo_bf, out, 4096, 2048, 2048);
}

// Round 17
// 300.544 us; speedup vs baseline: 1.0926x; 1.0123x over previous
//
#include <hip/hip_runtime.h>
#include <hip/hip_bf16.h>

#define DEVI __device__ __forceinline__

// ---- constants for this problem ----
// B=2, S=2048, D=2048, H=16, KV=4, HD=128, G=H/KV=4
// M = B*S = 4096; N_qkv = 5120 (4096 q+gate, 512 k, 512 v); K = 2048.

typedef __attribute__((ext_vector_type(8))) short bfrag;          // 8 bf16 = 16B (4 VGPRs)
typedef __attribute__((ext_vector_type(4))) float facc;           // 4 f32 acc
typedef __attribute__((ext_vector_type(4))) float f4v;
typedef __attribute__((ext_vector_type(4))) unsigned short us4;   // 4 bf16 = 8B

DEVI facc mfma16(bfrag a, bfrag b, facc c) {
  return __builtin_amdgcn_mfma_f32_16x16x32_bf16(a, b, c, 0, 0, 0);
}

DEVI void gl_lds16(const void* g, void* l) {
  // LDS dest must be WAVE-UNIFORM base; HW writes base + lane*16.
  __builtin_amdgcn_global_load_lds((__attribute__((address_space(1))) void*)g,
                                   (__attribute__((address_space(3))) void*)l,
                                   16, 0, 0);
}

// XOR swizzles (involutions, flip byte-addr bits 4..6 with low row bits).
DEVI int swz128(int a) { return a ^ (((a >> 7) & 7) << 4); }  // 128B-row tiles
DEVI int swz256(int a) { return a ^ (((a >> 8) & 7) << 4); }  // 256B-row tiles

DEVI unsigned short f2bu(float f) {
  __hip_bfloat16 h = __float2bfloat16(f);
  return *reinterpret_cast<unsigned short*>(&h);
}

// ---------------- fused cast f32 -> bf16 (all 5 tensors, one dispatch) ----------------
// segments (float4 units): x 2097152 | Wq 2097152 | Wk 262144 | Wv 262144 | Wo 1048576
__global__ __launch_bounds__(256) void cast_all(const float* __restrict__ x,
                                                const float* __restrict__ Wq,
                                                const float* __restrict__ Wk,
                                                const float* __restrict__ Wv,
                                                const float* __restrict__ Wo,
                                                unsigned short* __restrict__ x_bf,
                                                unsigned short* __restrict__ wqkv,
                                                unsigned short* __restrict__ wo_bf) {
  for (int i = blockIdx.x * 256 + threadIdx.x; i < 5767168; i += gridDim.x * 256) {
    const float* src; unsigned short* dst; int j;
    if (i < 2097152)      { src = x;  dst = x_bf;           j = i; }
    else if (i < 4194304) { src = Wq; dst = wqkv;           j = i - 2097152; }
    else if (i < 4456448) { src = Wk; dst = wqkv + 8388608; j = i - 4194304; }
    else if (i < 4718592) { src = Wv; dst = wqkv + 9437184; j = i - 4456448; }
    else                  { src = Wo; dst = wo_bf;          j = i - 4718592; }
    f4v v = ((const f4v*)src)[j];
    us4 o;
    o[0] = f2bu(v[0]); o[1] = f2bu(v[1]); o[2] = f2bu(v[2]); o[3] = f2bu(v[3]);
    ((us4*)dst)[j] = o;
  }
}

// ---------------- GEMM: C[M][N] = A[M][K] * B[N][K]^T (both row-major, K contig) ----
// 128x128 tile, BK=64 (one barrier pair per 64-K), 4 waves (2x2 of 64x64),
// T2 both-sides swizzle on As/Bs (128B rows), T1 XCD-chunked block swizzle.
template <typename OUT_T>
__global__ __launch_bounds__(256) void gemm_bt(const __hip_bfloat16* __restrict__ A,
                                               const __hip_bfloat16* __restrict__ Bm,
                                               OUT_T* __restrict__ C,
                                               int M, int N, int K) {
  __shared__ __attribute__((aligned(16))) __hip_bfloat16 As[128 * 64];  // 16KB
  __shared__ __attribute__((aligned(16))) __hip_bfloat16 Bs[128 * 64];  // 16KB
  // XCD-chunked bijective remap (nwg % 8 == 0 for all our launches)
  const int bid = blockIdx.y * gridDim.x + blockIdx.x;
  const int cpx = (gridDim.x * gridDim.y) >> 3;
  const int wg = (bid & 7) * cpx + (bid >> 3);
  const int n0 = (wg % gridDim.x) * 128, m0 = (wg / gridDim.x) * 128;
  const int tid = threadIdx.x, wave = tid >> 6, lane = tid & 63;
  const int lr = lane & 15, lg = lane >> 4;
  const int wr = wave >> 1, wc = wave & 1;

  facc acc[4][4];
#pragma unroll
  for (int m = 0; m < 4; ++m)
#pragma unroll
    for (int n = 0; n < 4; ++n) acc[m][n] = (facc){0.f, 0.f, 0.f, 0.f};

  const char* Ag = (const char*)A;
  const char* Bg = (const char*)Bm;
  const size_t rowb = (size_t)K * 2;

  for (int k0 = 0; k0 < K; k0 += 64) {
#pragma unroll
    for (int i = 0; i < 4; ++i) {
      const int wb = i * 4096 + wave * 1024;   // wave-uniform LDS byte base
      const int bo = wb + lane * 16;           // this lane's LDS byte slot
      const int row = bo >> 7;                 // 128B per row (64 bf16)
      const int kb = swz128(bo) & 127;         // pre-swizzled within-row offset
      gl_lds16(Ag + (size_t)(m0 + row) * rowb + (size_t)k0 * 2 + kb, (char*)As + wb);
      gl_lds16(Bg + (size_t)(n0 + row) * rowb + (size_t)k0 * 2 + kb, (char*)Bs + wb);
    }
    __syncthreads();
#pragma unroll
    for (int kk = 0; kk < 2; ++kk) {
      bfrag af[4], bf[4];
#pragma unroll
      for (int m = 0; m < 4; ++m)
        af[m] = *(const bfrag*)((const char*)As +
                    ((((wr * 64 + m * 16 + lr) << 7) + kk * 64 + lg * 16) ^ ((lr & 7) << 4)));
#pragma unroll
      for (int n = 0; n < 4; ++n)
        bf[n] = *(const bfrag*)((const char*)Bs +
                    ((((wc * 64 + n * 16 + lr) << 7) + kk * 64 + lg * 16) ^ ((lr & 7) << 4)));
#pragma unroll
      for (int m = 0; m < 4; ++m)
#pragma unroll
        for (int n = 0; n < 4; ++n) acc[m][n] = mfma16(af[m], bf[n], acc[m][n]);
    }
    __syncthreads();
  }

#pragma unroll
  for (int m = 0; m < 4; ++m)
#pragma unroll
    for (int n = 0; n < 4; ++n)
#pragma unroll
      for (int r = 0; r < 4; ++r) {
        const int row = m0 + wr * 64 + m * 16 + lg * 4 + r;  // verified C/D layout
        const int col = n0 + wc * 64 + n * 16 + lr;
        float v = acc[m][n][r];
        if constexpr (sizeof(OUT_T) == 4) C[(size_t)row * N + col] = v;
        else                              C[(size_t)row * N + col] = __float2bfloat16(v);
      }
}

// ---------------- fused prep: q-norm+RoPE | k-norm+RoPE | V-transpose ----------------
// One dispatch, 20992 blocks x 256 thr; selector on blockIdx.x (wave-uniform).
//   [0, 16384)      q-head RMSNorm+RoPE  -> Qb[b][h][s][d]
//   [16384, 20480)  k-head RMSNorm+RoPE  -> Kb[b][kv][s][d]
//   [20480, 20992)  V transpose          -> vt[b][kv][d][s]
__global__ __launch_bounds__(256) void fused_prep(const __hip_bfloat16* __restrict__ qkv,
                                                  const float* __restrict__ qw,
                                                  const float* __restrict__ kw,
                                                  const float* __restrict__ fc,
                                                  __hip_bfloat16* __restrict__ Qb,
                                                  __hip_bfloat16* __restrict__ Kb,
                                                  __hip_bfloat16* __restrict__ vt) {
  const int bid = blockIdx.x;
  if (bid < 16384) {
    // ---- q-norm + rope: one wave per (b,s,h); lane holds pair (d, d+64) ----
    int item = bid * 4 + (threadIdx.x >> 6);  // (b*S+s)*H + h
    int lane = threadIdx.x & 63;
    int h = item & 15, bs = item >> 4, s = bs & 2047, b = bs >> 11;
    size_t base = (size_t)bs * 5120 + h * 256;
    float e1 = __bfloat162float(qkv[base + lane]);
    float e2 = __bfloat162float(qkv[base + 64 + lane]);
    float ss = e1 * e1 + e2 * e2;
#pragma unroll
    for (int d = 1; d < 64; d <<= 1) ss += __shfl_xor(ss, d);
    float rr = rsqrtf(ss * (1.0f / 128.0f) + 1e-6f);
    float n1 = e1 * rr * (1.0f + qw[lane]);
    float n2 = e2 * rr * (1.0f + qw[lane + 64]);
    float cs = fc[s * 128 + lane], sn = fc[s * 128 + 64 + lane];
    size_t ob = ((size_t)((b * 16 + h) * 2048) + s) * 128;
    Qb[ob + lane]      = __float2bfloat16(n1 * cs - n2 * sn);
    Qb[ob + 64 + lane] = __float2bfloat16(n2 * cs + n1 * sn);
  } else if (bid < 20480) {
    // ---- k-norm + rope ----
    int item = (bid - 16384) * 4 + (threadIdx.x >> 6);  // (b*S+s)*KV + kv
    int lane = threadIdx.x & 63;
    int kv = item & 3, bs = item >> 2, s = bs & 2047, b = bs >> 11;
    size_t base = (size_t)bs * 5120 + 4096 + kv * 128;
    float e1 = __bfloat162float(qkv[base + lane]);
    float e2 = __bfloat162float(qkv[base + 64 + lane]);
    float ss = e1 * e1 + e2 * e2;
#pragma unroll
    for (int d = 1; d < 64; d <<= 1) ss += __shfl_xor(ss, d);
    float rr = rsqrtf(ss * (1.0f / 128.0f) + 1e-6f);
    float n1 = e1 * rr * (1.0f + kw[lane]);
    float n2 = e2 * rr * (1.0f + kw[lane + 64]);
    float cs = fc[s * 128 + lane], sn = fc[s * 128 + 64 + lane];
    size_t ob = ((size_t)((b * 4 + kv) * 2048) + s) * 128;
    Kb[ob + lane]      = __float2bfloat16(n1 * cs - n2 * sn);
    Kb[ob + 64 + lane] = __float2bfloat16(n2 * cs + n1 * sn);
  } else {
    // ---- V transpose: 64x64 tile via padded LDS ----
    __shared__ __hip_bfloat16 tile[64][65];
    const int t = bid - 20480;                // 512 tiles = 32 x 2 x 8
    const int s0 = (t & 31) * 64, d0 = ((t >> 5) & 1) * 64, bk = t >> 6;
    const int b = bk >> 2, kv = bk & 3;
    const int tid = threadIdx.x;
#pragma unroll
    for (int i = 0; i < 16; ++i) {
      int e = i * 256 + tid;
      int rr2 = e >> 6, c = e & 63;  // rr2 = s-idx, c = d-idx
      tile[rr2][c] = qkv[(size_t)(b * 2048 + s0 + rr2) * 5120 + 4608 + kv * 128 + d0 + c];
    }
    __syncthreads();
#pragma unroll
    for (int i = 0; i < 16; ++i) {
      int e = i * 256 + tid;
      int rr2 = e >> 6, c = e & 63;  // rr2 = d-idx, c = s-idx
      vt[(size_t)(bk * 128 + d0 + rr2) * 2048 + s0 + c] = tile[c][rr2];
    }
  }
}

// ---------------- causal GQA flash attention + sigmoid gate ----------------
// 512 blocks (1-D), 512 threads = 8 waves. QBLK=128: wave w owns the 16 q-rows
// [qt2*128 + w*16, +16); 8 waves SHARE each staged K/V tile. Balance: CU c
// hosts {n=c, n=c+256} with qt2 = {q, 15-q}. SWAPPED QK^T in-register softmax;
// T2 swizzle; T5 setprio; T13 defer-max (THR=8); wave-uniform causal-mask skip.
__global__ __launch_bounds__(512) void flash_attn(const __hip_bfloat16* __restrict__ Qb,
                                                  const __hip_bfloat16* __restrict__ Kb,
                                                  const __hip_bfloat16* __restrict__ Vt,
                                                  const __hip_bfloat16* __restrict__ qkv,
                                                  __hip_bfloat16* __restrict__ attn_g) {
  const int n_id = blockIdx.x;
  const int k = n_id >> 8, r = n_id & 255;
  const int qt2 = (k & 1) ? (15 - (r & 15)) : (r & 15);
  const int hb = (r >> 4) + (k << 4);       // 0..31 ; b == k
  const int h = hb & 15, b = hb >> 4;
  const int kvh = h >> 2;
  const int tid = threadIdx.x, wave = tid >> 6, lane = tid & 63;
  const int lr = lane & 15, lg = lane >> 4;

  __shared__ __attribute__((aligned(16))) __hip_bfloat16 Ks[64 * 128];   // swz256
  __shared__ __attribute__((aligned(16))) __hip_bfloat16 Vs[128 * 64];   // swz128
  __shared__ __attribute__((aligned(16))) __hip_bfloat16 Ps[8][16 * 64]; // per-wave

  bfrag qf[4];
  {
    const __hip_bfloat16* Qp =
        Qb + ((size_t)((b * 16 + h) * 2048) + qt2 * 128 + wave * 16 + lr) * 128;
#pragma unroll
    for (int kk = 0; kk < 4; ++kk) qf[kk] = *(const bfrag*)(Qp + kk * 32 + lg * 8);
  }

  facc o[8];
#pragma unroll
  for (int i = 0; i < 8; ++i) o[i] = (facc){0.f, 0.f, 0.f, 0.f};
  float m_s = -INFINITY;  // running max for q-row (lane&15)
  float l_s = 0.f;        // running denom for q-row (lane&15)
  const float sc = 0.08838834764831845f;  // 1/sqrt(128)

  const char* Kg0 = (const char*)(Kb + (size_t)((b * 4 + kvh) * 2048) * 128);
  const char* Vg0 = (const char*)(Vt + (size_t)((b * 4 + kvh) * 128) * 2048);
  char* PsW = (char*)&Ps[0][0] + wave * 2048;

  const int T = 2 * qt2 + 2;
  for (int t = 0; t < T; ++t) {
    // stage K tile (64x128, 16KB) + Vt tile across 8 waves (2 segs/wave),
    // pre-swizzling the GLOBAL source so swizzled reads see correct data.
#pragma unroll
    for (int i = 0; i < 2; ++i) {
      const int wb = i * 8192 + wave * 1024;
      const int bo = wb + lane * 16;
      gl_lds16(Kg0 + (size_t)t * 16384 + swz256(bo), (char*)Ks + wb);
      const int sa = swz128(bo);
      gl_lds16(Vg0 + (size_t)(bo >> 7) * 4096 + (size_t)t * 128 + (sa & 127),
               (char*)Vs + wb);
    }
    __syncthreads();

    // scores (swapped): st[n][r2] = S[kv = n*16+lg*4+r2][q = lr]
    facc st[4];
    __builtin_amdgcn_s_setprio(1);
#pragma unroll
    for (int n = 0; n < 4; ++n) {
      facc a = (facc){0.f, 0.f, 0.f, 0.f};
#pragma unroll
      for (int kk = 0; kk < 4; ++kk) {
        bfrag kf = *(const bfrag*)((const char*)Ks +
                       (((n * 16 + lr) * 256 + kk * 64 + lg * 16) ^ ((lr & 7) << 4)));
        a = mfma16(kf, qf[kk], a);   // SWAPPED: K as A, Q as B
      }
      st[n] = a;
    }
    __builtin_amdgcn_s_setprio(0);

    float pm = -INFINITY;
    if (t * 64 + 63 > qt2 * 128 + wave * 16) {   // wave-uniform: mask needed
      const int q_rel = qt2 * 128 + wave * 16 + lr - t * 64;
#pragma unroll
      for (int n = 0; n < 4; ++n)
#pragma unroll
        for (int r2 = 0; r2 < 4; ++r2) {
          float v = st[n][r2] * sc;
          if (n * 16 + lg * 4 + r2 > q_rel) v = -INFINITY;
          st[n][r2] = v;
          pm = fmaxf(pm, v);
        }
    } else {                                      // interior tile: no masking
#pragma unroll
      for (int n = 0; n < 4; ++n)
#pragma unroll
        for (int r2 = 0; r2 < 4; ++r2) {
          float v = st[n][r2] * sc;
          st[n][r2] = v;
          pm = fmaxf(pm, v);
        }
    }
    // cross-lane max over the 4 lanes holding this q-row (lg direction)
    pm = fmaxf(pm, __shfl_xor(pm, 16));
    pm = fmaxf(pm, __shfl_xor(pm, 32));

    // T13 defer-max: skip rescale when max growth <= 8 (first tile: m_s=-inf
    // makes pm - m_s = +inf -> no skip, so m_s becomes finite immediately).
    const bool skip = __all(pm <= m_s + 8.0f);
    float alpha = 1.0f;
    if (!skip) {
      float mn = fmaxf(m_s, pm);
      alpha = __expf(m_s - mn);
      m_s = mn;
    }

    float lsum = 0.f;
    us4 pw[4];
#pragma unroll
    for (int n = 0; n < 4; ++n)
#pragma unroll
      for (int r2 = 0; r2 < 4; ++r2) {
        float p = __expf(st[n][r2] - m_s);   // bounded by e^8 when deferred
        lsum += p;
        pw[n][r2] = f2bu(p);
      }
    lsum += __shfl_xor(lsum, 16);
    lsum += __shfl_xor(lsum, 32);
    l_s = l_s * alpha + lsum;

    // P write: 4 consecutive kv per lane per n-tile -> ds_write_b64
#pragma unroll
    for (int n = 0; n < 4; ++n) {
      const int byte = lr * 128 + n * 32 + lg * 8;
      *(us4*)(PsW + (byte ^ ((lr & 7) << 4))) = pw[n];
    }

    // rescale O only when max moved (acc layout rows q = lg*4+r2)
    if (!skip) {
      float alpha_acc[4];
#pragma unroll
      for (int r2 = 0; r2 < 4; ++r2) alpha_acc[r2] = __shfl(alpha, lg * 4 + r2);
#pragma unroll
      for (int nn = 0; nn < 8; ++nn)
#pragma unroll
        for (int r2 = 0; r2 < 4; ++r2) o[nn][r2] *= alpha_acc[r2];
    }

    // O += P (16x64) @ V (64x128)   (compiler inserts the Ps RAW lgkmcnt)
    __builtin_amdgcn_s_setprio(1);
#pragma unroll
    for (int kk2 = 0; kk2 < 2; ++kk2) {
      bfrag pa = *(const bfrag*)((const char*)PsW +
                     ((lr * 128 + kk2 * 64 + lg * 16) ^ ((lr & 7) << 4)));
#pragma unroll
      for (int nn = 0; nn < 8; ++nn) {
        bfrag vb = *(const bfrag*)((const char*)Vs +
                       (((nn * 16 + lr) * 128 + kk2 * 64 + lg * 16) ^ ((lr & 7) << 4)));
        o[nn] = mfma16(pa, vb, o[nn]);
      }
    }
    __builtin_amdgcn_s_setprio(0);
    __syncthreads();  // before next tile's staging overwrites Ks/Vs
  }

  // epilogue: normalize, sigmoid-gate, store bf16 [b*S+q][h*128+d]
  float inv = 1.0f / l_s;             // stat layout (q = lr)
  float inv_acc[4];
#pragma unroll
  for (int r2 = 0; r2 < 4; ++r2) inv_acc[r2] = __shfl(inv, lg * 4 + r2);
  const int q_base = qt2 * 128 + wave * 16 + lg * 4;
#pragma unroll
  for (int r2 = 0; r2 < 4; ++r2) {
    int q = q_base + r2;
    const __hip_bfloat16* gp = qkv + (size_t)(b * 2048 + q) * 5120 + h * 256 + 128;
    __hip_bfloat16* op = attn_g + (size_t)(b * 2048 + q) * 2048 + h * 128;
#pragma unroll
    for (int nn = 0; nn < 8; ++nn) {
      int d = nn * 16 + lr;
      float g = __bfloat162float(gp[d]);
      float sig = 1.0f / (1.0f + __expf(-g));
      op[d] = __float2bfloat16(o[nn][r2] * inv_acc[r2] * sig);
    }
  }
}

// ---------------- launch ----------------
extern "C" void kernel_launch(void* const* d_in, const int* in_sizes, int n_in,
                              void* d_out, int out_size, void* d_ws, size_t ws_size,
                              hipStream_t stream) {
  (void)in_sizes; (void)n_in; (void)out_size; (void)ws_size;
  const float* x  = (const float*)d_in[0];
  const float* fc = (const float*)d_in[1];
  const float* Wq = (const float*)d_in[2];
  const float* Wk = (const float*)d_in[3];
  const float* Wv = (const float*)d_in[4];
  const float* Wo = (const float*)d_in[5];
  const float* qw = (const float*)d_in[6];
  const float* kw = (const float*)d_in[7];
  float* out = (float*)d_out;
  char* ws = (char*)d_ws;

  // workspace layout (bytes), total 92,274,688
  auto* x_bf   = (__hip_bfloat16*)(ws + 0);          // 16,777,216  [4096][2048]
  auto* wqkv   = (__hip_bfloat16*)(ws + 16777216);   // 20,971,520  [5120][2048]
  auto* wo_bf  = (__hip_bfloat16*)(ws + 37748736);   //  8,388,608  [2048][2048]
  auto* qkvraw = (__hip_bfloat16*)(ws + 46137344);   // 41,943,040  [4096][5120]
  auto* vt     = (__hip_bfloat16*)(ws + 88080384);   //  4,194,304  [b][kv][128][2048]
  auto* attn_g = x_bf;                               // alias: x_bf dead after QKV GEMM
  auto* Qb     = wqkv;                               // alias: weights dead after GEMM
  auto* Kb     = (__hip_bfloat16*)(ws + 33554432);   //  4,194,304 (tail of wqkv region)

  // fused cast of all five f32 tensors to bf16 (one dispatch)
  cast_all<<<2048, 256, 0, stream>>>(x, Wq, Wk, Wv, Wo,
                                     (unsigned short*)x_bf,
                                     (unsigned short*)wqkv,
                                     (unsigned short*)wo_bf);

  // QKV projection: [4096][5120] = x_bf @ wqkv^T
  gemm_bt<__hip_bfloat16><<<dim3(40, 32), 256, 0, stream>>>(x_bf, wqkv, qkvraw, 4096, 5120, 2048);

  // fused q-norm/rope + k-norm/rope + V-transpose (one dispatch)
  fused_prep<<<20992, 256, 0, stream>>>(qkvraw, qw, kw, fc, Qb, Kb, vt);

  flash_attn<<<512, 512, 0, stream>>>(Qb, Kb, vt, qkvraw, attn_g);

  // output projection: d_out[4096][2048] = attn_g @ wo_bf^T (f32 out)
  gemm_bt<float><<<dim3(16, 32), 256, 0, stream>>>(attn_g, wo_bf, out, 4096, 2048, 2048);
}

// Round 18
// 278.021 us; speedup vs baseline: 1.1811x; 1.0810x over previous
//
#include <hip/hip_runtime.h>
#include <hip/hip_bf16.h>

#define DEVI __device__ __forceinline__

// ---- constants for this problem ----
// B=2, S=2048, D=2048, H=16, KV=4, HD=128, G=H/KV=4
// M = B*S = 4096; N_qkv = 5120 (4096 q+gate, 512 k, 512 v); K = 2048.

typedef __attribute__((ext_vector_type(8))) short bfrag;          // 8 bf16 = 16B (4 VGPRs)
typedef __attribute__((ext_vector_type(4))) float facc;           // 4 f32 acc
typedef __attribute__((ext_vector_type(4))) float f4v;
typedef __attribute__((ext_vector_type(4))) unsigned short us4;   // 4 bf16 = 8B

DEVI facc mfma16(bfrag a, bfrag b, facc c) {
  return __builtin_amdgcn_mfma_f32_16x16x32_bf16(a, b, c, 0, 0, 0);
}

DEVI void gl_lds16(const void* g, void* l) {
  // LDS dest must be WAVE-UNIFORM base; HW writes base + lane*16.
  __builtin_amdgcn_global_load_lds((__attribute__((address_space(1))) void*)g,
                                   (__attribute__((address_space(3))) void*)l,
                                   16, 0, 0);
}

// XOR swizzles (involutions, flip byte-addr bits 4..6 with low row bits).
DEVI int swz128(int a) { return a ^ (((a >> 7) & 7) << 4); }  // 128B-row tiles
DEVI int swz256(int a) { return a ^ (((a >> 8) & 7) << 4); }  // 256B-row tiles

DEVI unsigned short f2bu(float f) {
  __hip_bfloat16 h = __float2bfloat16(f);
  return *reinterpret_cast<unsigned short*>(&h);
}

// ---------------- fused cast f32 -> bf16 (all 5 tensors, one dispatch) ----------------
// segments (float4 units): x 2097152 | Wq 2097152 | Wk 262144 | Wv 262144 | Wo 1048576
__global__ __launch_bounds__(256) void cast_all(const float* __restrict__ x,
                                                const float* __restrict__ Wq,
                                                const float* __restrict__ Wk,
                                                const float* __restrict__ Wv,
                                                const float* __restrict__ Wo,
                                                unsigned short* __restrict__ x_bf,
                                                unsigned short* __restrict__ wqkv,
                                                unsigned short* __restrict__ wo_bf) {
  for (int i = blockIdx.x * 256 + threadIdx.x; i < 5767168; i += gridDim.x * 256) {
    const float* src; unsigned short* dst; int j;
    if (i < 2097152)      { src = x;  dst = x_bf;           j = i; }
    else if (i < 4194304) { src = Wq; dst = wqkv;           j = i - 2097152; }
    else if (i < 4456448) { src = Wk; dst = wqkv + 8388608; j = i - 4194304; }
    else if (i < 4718592) { src = Wv; dst = wqkv + 9437184; j = i - 4456448; }
    else                  { src = Wo; dst = wo_bf;          j = i - 4718592; }
    f4v v = ((const f4v*)src)[j];
    us4 o;
    o[0] = f2bu(v[0]); o[1] = f2bu(v[1]); o[2] = f2bu(v[2]); o[3] = f2bu(v[3]);
    ((us4*)dst)[j] = o;
  }
}

// ---------------- GEMM: C[M][N] = A[M][K] * B[N][K]^T (both row-major, K contig) ----
// 128x128 tile, BK=64 (one barrier pair per 64-K), 4 waves (2x2 of 64x64),
// T2 both-sides swizzle on As/Bs (128B rows), T1 XCD-chunked block swizzle.
template <typename OUT_T>
__global__ __launch_bounds__(256) void gemm_bt(const __hip_bfloat16* __restrict__ A,
                                               const __hip_bfloat16* __restrict__ Bm,
                                               OUT_T* __restrict__ C,
                                               int M, int N, int K) {
  __shared__ __attribute__((aligned(16))) __hip_bfloat16 As[128 * 64];  // 16KB
  __shared__ __attribute__((aligned(16))) __hip_bfloat16 Bs[128 * 64];  // 16KB
  // XCD-chunked bijective remap (nwg % 8 == 0 for all our launches)
  const int bid = blockIdx.y * gridDim.x + blockIdx.x;
  const int cpx = (gridDim.x * gridDim.y) >> 3;
  const int wg = (bid & 7) * cpx + (bid >> 3);
  const int n0 = (wg % gridDim.x) * 128, m0 = (wg / gridDim.x) * 128;
  const int tid = threadIdx.x, wave = tid >> 6, lane = tid & 63;
  const int lr = lane & 15, lg = lane >> 4;
  const int wr = wave >> 1, wc = wave & 1;

  facc acc[4][4];
#pragma unroll
  for (int m = 0; m < 4; ++m)
#pragma unroll
    for (int n = 0; n < 4; ++n) acc[m][n] = (facc){0.f, 0.f, 0.f, 0.f};

  const char* Ag = (const char*)A;
  const char* Bg = (const char*)Bm;
  const size_t rowb = (size_t)K * 2;

  for (int k0 = 0; k0 < K; k0 += 64) {
#pragma unroll
    for (int i = 0; i < 4; ++i) {
      const int wb = i * 4096 + wave * 1024;   // wave-uniform LDS byte base
      const int bo = wb + lane * 16;           // this lane's LDS byte slot
      const int row = bo >> 7;                 // 128B per row (64 bf16)
      const int kb = swz128(bo) & 127;         // pre-swizzled within-row offset
      gl_lds16(Ag + (size_t)(m0 + row) * rowb + (size_t)k0 * 2 + kb, (char*)As + wb);
      gl_lds16(Bg + (size_t)(n0 + row) * rowb + (size_t)k0 * 2 + kb, (char*)Bs + wb);
    }
    __syncthreads();
#pragma unroll
    for (int kk = 0; kk < 2; ++kk) {
      bfrag af[4], bf[4];
#pragma unroll
      for (int m = 0; m < 4; ++m)
        af[m] = *(const bfrag*)((const char*)As +
                    ((((wr * 64 + m * 16 + lr) << 7) + kk * 64 + lg * 16) ^ ((lr & 7) << 4)));
#pragma unroll
      for (int n = 0; n < 4; ++n)
        bf[n] = *(const bfrag*)((const char*)Bs +
                    ((((wc * 64 + n * 16 + lr) << 7) + kk * 64 + lg * 16) ^ ((lr & 7) << 4)));
#pragma unroll
      for (int m = 0; m < 4; ++m)
#pragma unroll
        for (int n = 0; n < 4; ++n) acc[m][n] = mfma16(af[m], bf[n], acc[m][n]);
    }
    __syncthreads();
  }

#pragma unroll
  for (int m = 0; m < 4; ++m)
#pragma unroll
    for (int n = 0; n < 4; ++n)
#pragma unroll
      for (int r = 0; r < 4; ++r) {
        const int row = m0 + wr * 64 + m * 16 + lg * 4 + r;  // verified C/D layout
        const int col = n0 + wc * 64 + n * 16 + lr;
        float v = acc[m][n][r];
        if constexpr (sizeof(OUT_T) == 4) C[(size_t)row * N + col] = v;
        else                              C[(size_t)row * N + col] = __float2bfloat16(v);
      }
}

// ---------------- fused prep: q-norm+RoPE | k-norm+RoPE | V-transpose ----------------
// One dispatch, 20992 blocks x 256 thr; selector on blockIdx.x (wave-uniform).
//   [0, 16384)      q-head RMSNorm+RoPE  -> Qb[b][h][s][d]
//   [16384, 20480)  k-head RMSNorm+RoPE  -> Kb[b][kv][s][d]
//   [20480, 20992)  V transpose          -> vt[b][kv][d][s]
__global__ __launch_bounds__(256) void fused_prep(const __hip_bfloat16* __restrict__ qkv,
                                                  const float* __restrict__ qw,
                                                  const float* __restrict__ kw,
                                                  const float* __restrict__ fc,
                                                  __hip_bfloat16* __restrict__ Qb,
                                                  __hip_bfloat16* __restrict__ Kb,
                                                  __hip_bfloat16* __restrict__ vt) {
  const int bid = blockIdx.x;
  if (bid < 16384) {
    // ---- q-norm + rope: one wave per (b,s,h); lane holds pair (d, d+64) ----
    int item = bid * 4 + (threadIdx.x >> 6);  // (b*S+s)*H + h
    int lane = threadIdx.x & 63;
    int h = item & 15, bs = item >> 4, s = bs & 2047, b = bs >> 11;
    size_t base = (size_t)bs * 5120 + h * 256;
    float e1 = __bfloat162float(qkv[base + lane]);
    float e2 = __bfloat162float(qkv[base + 64 + lane]);
    float ss = e1 * e1 + e2 * e2;
#pragma unroll
    for (int d = 1; d < 64; d <<= 1) ss += __shfl_xor(ss, d);
    float rr = rsqrtf(ss * (1.0f / 128.0f) + 1e-6f);
    float n1 = e1 * rr * (1.0f + qw[lane]);
    float n2 = e2 * rr * (1.0f + qw[lane + 64]);
    float cs = fc[s * 128 + lane], sn = fc[s * 128 + 64 + lane];
    size_t ob = ((size_t)((b * 16 + h) * 2048) + s) * 128;
    Qb[ob + lane]      = __float2bfloat16(n1 * cs - n2 * sn);
    Qb[ob + 64 + lane] = __float2bfloat16(n2 * cs + n1 * sn);
  } else if (bid < 20480) {
    // ---- k-norm + rope ----
    int item = (bid - 16384) * 4 + (threadIdx.x >> 6);  // (b*S+s)*KV + kv
    int lane = threadIdx.x & 63;
    int kv = item & 3, bs = item >> 2, s = bs & 2047, b = bs >> 11;
    size_t base = (size_t)bs * 5120 + 4096 + kv * 128;
    float e1 = __bfloat162float(qkv[base + lane]);
    float e2 = __bfloat162float(qkv[base + 64 + lane]);
    float ss = e1 * e1 + e2 * e2;
#pragma unroll
    for (int d = 1; d < 64; d <<= 1) ss += __shfl_xor(ss, d);
    float rr = rsqrtf(ss * (1.0f / 128.0f) + 1e-6f);
    float n1 = e1 * rr * (1.0f + kw[lane]);
    float n2 = e2 * rr * (1.0f + kw[lane + 64]);
    float cs = fc[s * 128 + lane], sn = fc[s * 128 + 64 + lane];
    size_t ob = ((size_t)((b * 4 + kv) * 2048) + s) * 128;
    Kb[ob + lane]      = __float2bfloat16(n1 * cs - n2 * sn);
    Kb[ob + 64 + lane] = __float2bfloat16(n2 * cs + n1 * sn);
  } else {
    // ---- V transpose: 64x64 tile via padded LDS ----
    __shared__ __hip_bfloat16 tile[64][65];
    const int t = bid - 20480;                // 512 tiles = 32 x 2 x 8
    const int s0 = (t & 31) * 64, d0 = ((t >> 5) & 1) * 64, bk = t >> 6;
    const int b = bk >> 2, kv = bk & 3;
    const int tid = threadIdx.x;
#pragma unroll
    for (int i = 0; i < 16; ++i) {
      int e = i * 256 + tid;
      int rr2 = e >> 6, c = e & 63;  // rr2 = s-idx, c = d-idx
      tile[rr2][c] = qkv[(size_t)(b * 2048 + s0 + rr2) * 5120 + 4608 + kv * 128 + d0 + c];
    }
    __syncthreads();
#pragma unroll
    for (int i = 0; i < 16; ++i) {
      int e = i * 256 + tid;
      int rr2 = e >> 6, c = e & 63;  // rr2 = d-idx, c = s-idx
      vt[(size_t)(bk * 128 + d0 + rr2) * 2048 + s0 + c] = tile[c][rr2];
    }
  }
}

// ---------------- causal GQA flash attention + sigmoid gate ----------------
// 512 blocks (2/CU) x 512 threads = 8 waves; DYNAMIC work-stealing via a
// device-scope atomic counter, tasks sorted LONGEST-FIRST (LPT): task i ->
// qt2 = 15 - (i>>5), hb = i&31. Each task = one 128-q-row tile; blocks loop
// grabbing tasks so CUs equalize (~34 tile-units each, 16 waves resident).
// Inner body identical to r16: SWAPPED QK^T in-register softmax, T2 swizzle,
// T5 setprio, T13 defer-max, wave-uniform causal-mask skip.
__global__ __launch_bounds__(512) void flash_attn(const __hip_bfloat16* __restrict__ Qb,
                                                  const __hip_bfloat16* __restrict__ Kb,
                                                  const __hip_bfloat16* __restrict__ Vt,
                                                  const __hip_bfloat16* __restrict__ qkv,
                                                  __hip_bfloat16* __restrict__ attn_g,
                                                  int* __restrict__ cnt) {
  const int tid = threadIdx.x, wave = tid >> 6, lane = tid & 63;
  const int lr = lane & 15, lg = lane >> 4;

  __shared__ __attribute__((aligned(16))) __hip_bfloat16 Ks[64 * 128];   // swz256
  __shared__ __attribute__((aligned(16))) __hip_bfloat16 Vs[128 * 64];   // swz128
  __shared__ __attribute__((aligned(16))) __hip_bfloat16 Ps[8][16 * 64]; // per-wave
  __shared__ int sh_task;

  char* PsW = (char*)&Ps[0][0] + wave * 2048;
  const float sc = 0.08838834764831845f;  // 1/sqrt(128)

  while (true) {
    if (tid == 0) sh_task = atomicAdd(cnt, 1);
    __syncthreads();
    const int task = sh_task;          // uniform across block
    if (task >= 512) break;

    const int qt2 = 15 - (task >> 5);  // longest-first (LPT)
    const int hb = task & 31;
    const int h = hb & 15, b = hb >> 4;
    const int kvh = h >> 2;

    bfrag qf[4];
    {
      const __hip_bfloat16* Qp =
          Qb + ((size_t)((b * 16 + h) * 2048) + qt2 * 128 + wave * 16 + lr) * 128;
#pragma unroll
      for (int kk = 0; kk < 4; ++kk) qf[kk] = *(const bfrag*)(Qp + kk * 32 + lg * 8);
    }

    facc o[8];
#pragma unroll
    for (int i = 0; i < 8; ++i) o[i] = (facc){0.f, 0.f, 0.f, 0.f};
    float m_s = -INFINITY;  // running max for q-row (lane&15)
    float l_s = 0.f;        // running denom for q-row (lane&15)

    const char* Kg0 = (const char*)(Kb + (size_t)((b * 4 + kvh) * 2048) * 128);
    const char* Vg0 = (const char*)(Vt + (size_t)((b * 4 + kvh) * 128) * 2048);

    const int T = 2 * qt2 + 2;
    for (int t = 0; t < T; ++t) {
      // stage K tile (64x128, 16KB) + Vt tile across 8 waves (2 segs/wave),
      // pre-swizzling the GLOBAL source so swizzled reads see correct data.
#pragma unroll
      for (int i = 0; i < 2; ++i) {
        const int wb = i * 8192 + wave * 1024;
        const int bo = wb + lane * 16;
        gl_lds16(Kg0 + (size_t)t * 16384 + swz256(bo), (char*)Ks + wb);
        const int sa = swz128(bo);
        gl_lds16(Vg0 + (size_t)(bo >> 7) * 4096 + (size_t)t * 128 + (sa & 127),
                 (char*)Vs + wb);
      }
      __syncthreads();

      // scores (swapped): st[n][r2] = S[kv = n*16+lg*4+r2][q = lr]
      facc st[4];
      __builtin_amdgcn_s_setprio(1);
#pragma unroll
      for (int n = 0; n < 4; ++n) {
        facc a = (facc){0.f, 0.f, 0.f, 0.f};
#pragma unroll
        for (int kk = 0; kk < 4; ++kk) {
          bfrag kf = *(const bfrag*)((const char*)Ks +
                         (((n * 16 + lr) * 256 + kk * 64 + lg * 16) ^ ((lr & 7) << 4)));
          a = mfma16(kf, qf[kk], a);   // SWAPPED: K as A, Q as B
        }
        st[n] = a;
      }
      __builtin_amdgcn_s_setprio(0);

      float pm = -INFINITY;
      if (t * 64 + 63 > qt2 * 128 + wave * 16) {   // wave-uniform: mask needed
        const int q_rel = qt2 * 128 + wave * 16 + lr - t * 64;
#pragma unroll
        for (int n = 0; n < 4; ++n)
#pragma unroll
          for (int r2 = 0; r2 < 4; ++r2) {
            float v = st[n][r2] * sc;
            if (n * 16 + lg * 4 + r2 > q_rel) v = -INFINITY;
            st[n][r2] = v;
            pm = fmaxf(pm, v);
          }
      } else {                                      // interior tile: no masking
#pragma unroll
        for (int n = 0; n < 4; ++n)
#pragma unroll
          for (int r2 = 0; r2 < 4; ++r2) {
            float v = st[n][r2] * sc;
            st[n][r2] = v;
            pm = fmaxf(pm, v);
          }
      }
      // cross-lane max over the 4 lanes holding this q-row (lg direction)
      pm = fmaxf(pm, __shfl_xor(pm, 16));
      pm = fmaxf(pm, __shfl_xor(pm, 32));

      // T13 defer-max: skip rescale when max growth <= 8 (first tile: m_s=-inf
      // -> no skip, so m_s becomes finite immediately).
      const bool skip = __all(pm <= m_s + 8.0f);
      float alpha = 1.0f;
      if (!skip) {
        float mn = fmaxf(m_s, pm);
        alpha = __expf(m_s - mn);
        m_s = mn;
      }

      float lsum = 0.f;
      us4 pw[4];
#pragma unroll
      for (int n = 0; n < 4; ++n)
#pragma unroll
        for (int r2 = 0; r2 < 4; ++r2) {
          float p = __expf(st[n][r2] - m_s);   // bounded by e^8 when deferred
          lsum += p;
          pw[n][r2] = f2bu(p);
        }
      lsum += __shfl_xor(lsum, 16);
      lsum += __shfl_xor(lsum, 32);
      l_s = l_s * alpha + lsum;

      // P write: 4 consecutive kv per lane per n-tile -> ds_write_b64
#pragma unroll
      for (int n = 0; n < 4; ++n) {
        const int byte = lr * 128 + n * 32 + lg * 8;
        *(us4*)(PsW + (byte ^ ((lr & 7) << 4))) = pw[n];
      }

      // rescale O only when max moved (acc layout rows q = lg*4+r2)
      if (!skip) {
        float alpha_acc[4];
#pragma unroll
        for (int r2 = 0; r2 < 4; ++r2) alpha_acc[r2] = __shfl(alpha, lg * 4 + r2);
#pragma unroll
        for (int nn = 0; nn < 8; ++nn)
#pragma unroll
          for (int r2 = 0; r2 < 4; ++r2) o[nn][r2] *= alpha_acc[r2];
      }

      // O += P (16x64) @ V (64x128)   (compiler inserts the Ps RAW lgkmcnt)
      __builtin_amdgcn_s_setprio(1);
#pragma unroll
      for (int kk2 = 0; kk2 < 2; ++kk2) {
        bfrag pa = *(const bfrag*)((const char*)PsW +
                       ((lr * 128 + kk2 * 64 + lg * 16) ^ ((lr & 7) << 4)));
#pragma unroll
        for (int nn = 0; nn < 8; ++nn) {
          bfrag vb = *(const bfrag*)((const char*)Vs +
                         (((nn * 16 + lr) * 128 + kk2 * 64 + lg * 16) ^ ((lr & 7) << 4)));
          o[nn] = mfma16(pa, vb, o[nn]);
        }
      }
      __builtin_amdgcn_s_setprio(0);
      __syncthreads();  // before next tile's staging overwrites Ks/Vs
    }

    // epilogue: normalize, sigmoid-gate, store bf16 [b*S+q][h*128+d]
    float inv = 1.0f / l_s;             // stat layout (q = lr)
    float inv_acc[4];
#pragma unroll
    for (int r2 = 0; r2 < 4; ++r2) inv_acc[r2] = __shfl(inv, lg * 4 + r2);
    const int q_base = qt2 * 128 + wave * 16 + lg * 4;
#pragma unroll
    for (int r2 = 0; r2 < 4; ++r2) {
      int q = q_base + r2;
      const __hip_bfloat16* gp = qkv + (size_t)(b * 2048 + q) * 5120 + h * 256 + 128;
      __hip_bfloat16* op = attn_g + (size_t)(b * 2048 + q) * 2048 + h * 128;
#pragma unroll
      for (int nn = 0; nn < 8; ++nn) {
        int d = nn * 16 + lr;
        float g = __bfloat162float(gp[d]);
        float sig = 1.0f / (1.0f + __expf(-g));
        op[d] = __float2bfloat16(o[nn][r2] * inv_acc[r2] * sig);
      }
    }
  }
}

// ---------------- launch ----------------
extern "C" void kernel_launch(void* const* d_in, const int* in_sizes, int n_in,
                              void* d_out, int out_size, void* d_ws, size_t ws_size,
                              hipStream_t stream) {
  (void)in_sizes; (void)n_in; (void)out_size; (void)ws_size;
  const float* x  = (const float*)d_in[0];
  const float* fc = (const float*)d_in[1];
  const float* Wq = (const float*)d_in[2];
  const float* Wk = (const float*)d_in[3];
  const float* Wv = (const float*)d_in[4];
  const float* Wo = (const float*)d_in[5];
  const float* qw = (const float*)d_in[6];
  const float* kw = (const float*)d_in[7];
  float* out = (float*)d_out;
  char* ws = (char*)d_ws;

  // workspace layout (bytes), total 92,274,688
  auto* x_bf   = (__hip_bfloat16*)(ws + 0);          // 16,777,216  [4096][2048]
  auto* wqkv   = (__hip_bfloat16*)(ws + 16777216);   // 20,971,520  [5120][2048]
  auto* wo_bf  = (__hip_bfloat16*)(ws + 37748736);   //  8,388,608  [2048][2048]
  auto* qkvraw = (__hip_bfloat16*)(ws + 46137344);   // 41,943,040  [4096][5120]
  auto* vt     = (__hip_bfloat16*)(ws + 88080384);   //  4,194,304  [b][kv][128][2048]
  auto* attn_g = x_bf;                               // alias: x_bf dead after QKV GEMM
  auto* Qb     = wqkv;                               // alias: weights dead after GEMM
  auto* Kb     = (__hip_bfloat16*)(ws + 33554432);   //  4,194,304 (tail of wqkv region)
  // task counter: first element of qkvraw's v-slice (row 0, col 4608) —
  // written by QKV GEMM, consumed by fused_prep's vtrans, DEAD during flash.
  int* cnt = (int*)(ws + 46137344 + 4608 * 2);

  // fused cast of all five f32 tensors to bf16 (one dispatch)
  cast_all<<<2048, 256, 0, stream>>>(x, Wq, Wk, Wv, Wo,
                                     (unsigned short*)x_bf,
                                     (unsigned short*)wqkv,
                                     (unsigned short*)wo_bf);

  // QKV projection: [4096][5120] = x_bf @ wqkv^T
  gemm_bt<__hip_bfloat16><<<dim3(40, 32), 256, 0, stream>>>(x_bf, wqkv, qkvraw, 4096, 5120, 2048);

  // fused q-norm/rope + k-norm/rope + V-transpose (one dispatch)
  fused_prep<<<20992, 256, 0, stream>>>(qkvraw, qw, kw, fc, Qb, Kb, vt);

  // reset the work-stealing counter (graph-capture-safe async memset)
  hipMemsetAsync(cnt, 0, 4, stream);

  flash_attn<<<512, 512, 0, stream>>>(Qb, Kb, vt, qkvraw, attn_g, cnt);

  // output projection: d_out[4096][2048] = attn_g @ wo_bf^T (f32 out)
  gemm_bt<float><<<dim3(16, 32), 256, 0, stream>>>(attn_g, wo_bf, out, 4096, 2048, 2048);
}

// Round 19
// 264.743 us; speedup vs baseline: 1.2403x; 1.0502x over previous
//
#include <hip/hip_runtime.h>
#include <hip/hip_bf16.h>

#define DEVI __device__ __forceinline__

// ---- constants for this problem ----
// B=2, S=2048, D=2048, H=16, KV=4, HD=128, G=H/KV=4
// M = B*S = 4096; N_qkv = 5120 (4096 q+gate, 512 k, 512 v); K = 2048.

typedef __attribute__((ext_vector_type(8))) short bfrag;          // 8 bf16 = 16B (4 VGPRs)
typedef __attribute__((ext_vector_type(4))) float facc;           // 4 f32 acc
typedef __attribute__((ext_vector_type(4))) float f4v;
typedef __attribute__((ext_vector_type(4))) unsigned short us4;   // 4 bf16 = 8B

DEVI facc mfma16(bfrag a, bfrag b, facc c) {
  return __builtin_amdgcn_mfma_f32_16x16x32_bf16(a, b, c, 0, 0, 0);
}

DEVI void gl_lds16(const void* g, void* l) {
  // LDS dest must be WAVE-UNIFORM base; HW writes base + lane*16.
  __builtin_amdgcn_global_load_lds((__attribute__((address_space(1))) void*)g,
                                   (__attribute__((address_space(3))) void*)l,
                                   16, 0, 0);
}

// XOR swizzles (involutions, flip byte-addr bits 4..6 with low row bits).
DEVI int swz128(int a) { return a ^ (((a >> 7) & 7) << 4); }  // 128B-row tiles
DEVI int swz256(int a) { return a ^ (((a >> 8) & 7) << 4); }  // 256B-row tiles

DEVI unsigned short f2bu(float f) {
  __hip_bfloat16 h = __float2bfloat16(f);
  return *reinterpret_cast<unsigned short*>(&h);
}

// ---------------- fused cast f32 -> bf16 (all 5 tensors, one dispatch) ----------------
// segments (float4 units): x 2097152 | Wq 2097152 | Wk 262144 | Wv 262144 | Wo 1048576
__global__ __launch_bounds__(256) void cast_all(const float* __restrict__ x,
                                                const float* __restrict__ Wq,
                                                const float* __restrict__ Wk,
                                                const float* __restrict__ Wv,
                                                const float* __restrict__ Wo,
                                                unsigned short* __restrict__ x_bf,
                                                unsigned short* __restrict__ wqkv,
                                                unsigned short* __restrict__ wo_bf) {
  for (int i = blockIdx.x * 256 + threadIdx.x; i < 5767168; i += gridDim.x * 256) {
    const float* src; unsigned short* dst; int j;
    if (i < 2097152)      { src = x;  dst = x_bf;           j = i; }
    else if (i < 4194304) { src = Wq; dst = wqkv;           j = i - 2097152; }
    else if (i < 4456448) { src = Wk; dst = wqkv + 8388608; j = i - 4194304; }
    else if (i < 4718592) { src = Wv; dst = wqkv + 9437184; j = i - 4456448; }
    else                  { src = Wo; dst = wo_bf;          j = i - 4718592; }
    f4v v = ((const f4v*)src)[j];
    us4 o;
    o[0] = f2bu(v[0]); o[1] = f2bu(v[1]); o[2] = f2bu(v[2]); o[3] = f2bu(v[3]);
    ((us4*)dst)[j] = o;
  }
}

// ---------------- GEMM: C[M][N] = A[M][K] * B[N][K]^T (both row-major, K contig) ----
// 128x128 tile, BK=64 (one barrier pair per 64-K), 4 waves (2x2 of 64x64),
// T2 both-sides swizzle on As/Bs (128B rows).
// 2-D XCD SUPER-TILING: each XCD (bid&7 under round-robin dispatch) owns a
// rectangular region of the tile grid -> per-XCD unique A/B panels minimized
// (w+h instead of gridDim.x+h). XRECTN = rect count along n (must divide 8).
template <typename OUT_T>
__global__ __launch_bounds__(256) void gemm_bt(const __hip_bfloat16* __restrict__ A,
                                               const __hip_bfloat16* __restrict__ Bm,
                                               OUT_T* __restrict__ C,
                                               int M, int N, int K, int XRECTN) {
  __shared__ __attribute__((aligned(16))) __hip_bfloat16 As[128 * 64];  // 16KB
  __shared__ __attribute__((aligned(16))) __hip_bfloat16 Bs[128 * 64];  // 16KB
  const int bid = blockIdx.y * gridDim.x + blockIdx.x;
  const int xcd = bid & 7, li = bid >> 3;
  const int xrm = 8 / XRECTN;
  const int wrect = gridDim.x / XRECTN, hrect = gridDim.y / xrm;
  const int n0 = ((xcd % XRECTN) * wrect + li % wrect) * 128;
  const int m0 = ((xcd / XRECTN) * hrect + li / wrect) * 128;
  const int tid = threadIdx.x, wave = tid >> 6, lane = tid & 63;
  const int lr = lane & 15, lg = lane >> 4;
  const int wr = wave >> 1, wc = wave & 1;

  facc acc[4][4];
#pragma unroll
  for (int m = 0; m < 4; ++m)
#pragma unroll
    for (int n = 0; n < 4; ++n) acc[m][n] = (facc){0.f, 0.f, 0.f, 0.f};

  const char* Ag = (const char*)A;
  const char* Bg = (const char*)Bm;
  const size_t rowb = (size_t)K * 2;

  for (int k0 = 0; k0 < K; k0 += 64) {
#pragma unroll
    for (int i = 0; i < 4; ++i) {
      const int wb = i * 4096 + wave * 1024;   // wave-uniform LDS byte base
      const int bo = wb + lane * 16;           // this lane's LDS byte slot
      const int row = bo >> 7;                 // 128B per row (64 bf16)
      const int kb = swz128(bo) & 127;         // pre-swizzled within-row offset
      gl_lds16(Ag + (size_t)(m0 + row) * rowb + (size_t)k0 * 2 + kb, (char*)As + wb);
      gl_lds16(Bg + (size_t)(n0 + row) * rowb + (size_t)k0 * 2 + kb, (char*)Bs + wb);
    }
    __syncthreads();
#pragma unroll
    for (int kk = 0; kk < 2; ++kk) {
      bfrag af[4], bf[4];
#pragma unroll
      for (int m = 0; m < 4; ++m)
        af[m] = *(const bfrag*)((const char*)As +
                    ((((wr * 64 + m * 16 + lr) << 7) + kk * 64 + lg * 16) ^ ((lr & 7) << 4)));
#pragma unroll
      for (int n = 0; n < 4; ++n)
        bf[n] = *(const bfrag*)((const char*)Bs +
                    ((((wc * 64 + n * 16 + lr) << 7) + kk * 64 + lg * 16) ^ ((lr & 7) << 4)));
#pragma unroll
      for (int m = 0; m < 4; ++m)
#pragma unroll
        for (int n = 0; n < 4; ++n) acc[m][n] = mfma16(af[m], bf[n], acc[m][n]);
    }
    __syncthreads();
  }

#pragma unroll
  for (int m = 0; m < 4; ++m)
#pragma unroll
    for (int n = 0; n < 4; ++n)
#pragma unroll
      for (int r = 0; r < 4; ++r) {
        const int row = m0 + wr * 64 + m * 16 + lg * 4 + r;  // verified C/D layout
        const int col = n0 + wc * 64 + n * 16 + lr;
        float v = acc[m][n][r];
        if constexpr (sizeof(OUT_T) == 4) C[(size_t)row * N + col] = v;
        else                              C[(size_t)row * N + col] = __float2bfloat16(v);
      }
}

// ---------------- fused prep: q-norm+RoPE | k-norm+RoPE | V-transpose ----------------
// One dispatch, 20992 blocks x 256 thr; selector on blockIdx.x (wave-uniform).
//   [0, 16384)      q-head RMSNorm+RoPE  -> Qb[b][h][s][d]
//   [16384, 20480)  k-head RMSNorm+RoPE  -> Kb[b][kv][s][d]
//   [20480, 20992)  V transpose          -> vt[b][kv][d][s]
__global__ __launch_bounds__(256) void fused_prep(const __hip_bfloat16* __restrict__ qkv,
                                                  const float* __restrict__ qw,
                                                  const float* __restrict__ kw,
                                                  const float* __restrict__ fc,
                                                  __hip_bfloat16* __restrict__ Qb,
                                                  __hip_bfloat16* __restrict__ Kb,
                                                  __hip_bfloat16* __restrict__ vt) {
  const int bid = blockIdx.x;
  if (bid < 16384) {
    // ---- q-norm + rope: one wave per (b,s,h); lane holds pair (d, d+64) ----
    int item = bid * 4 + (threadIdx.x >> 6);  // (b*S+s)*H + h
    int lane = threadIdx.x & 63;
    int h = item & 15, bs = item >> 4, s = bs & 2047, b = bs >> 11;
    size_t base = (size_t)bs * 5120 + h * 256;
    float e1 = __bfloat162float(qkv[base + lane]);
    float e2 = __bfloat162float(qkv[base + 64 + lane]);
    float ss = e1 * e1 + e2 * e2;
#pragma unroll
    for (int d = 1; d < 64; d <<= 1) ss += __shfl_xor(ss, d);
    float rr = rsqrtf(ss * (1.0f / 128.0f) + 1e-6f);
    float n1 = e1 * rr * (1.0f + qw[lane]);
    float n2 = e2 * rr * (1.0f + qw[lane + 64]);
    float cs = fc[s * 128 + lane], sn = fc[s * 128 + 64 + lane];
    size_t ob = ((size_t)((b * 16 + h) * 2048) + s) * 128;
    Qb[ob + lane]      = __float2bfloat16(n1 * cs - n2 * sn);
    Qb[ob + 64 + lane] = __float2bfloat16(n2 * cs + n1 * sn);
  } else if (bid < 20480) {
    // ---- k-norm + rope ----
    int item = (bid - 16384) * 4 + (threadIdx.x >> 6);  // (b*S+s)*KV + kv
    int lane = threadIdx.x & 63;
    int kv = item & 3, bs = item >> 2, s = bs & 2047, b = bs >> 11;
    size_t base = (size_t)bs * 5120 + 4096 + kv * 128;
    float e1 = __bfloat162float(qkv[base + lane]);
    float e2 = __bfloat162float(qkv[base + 64 + lane]);
    float ss = e1 * e1 + e2 * e2;
#pragma unroll
    for (int d = 1; d < 64; d <<= 1) ss += __shfl_xor(ss, d);
    float rr = rsqrtf(ss * (1.0f / 128.0f) + 1e-6f);
    float n1 = e1 * rr * (1.0f + kw[lane]);
    float n2 = e2 * rr * (1.0f + kw[lane + 64]);
    float cs = fc[s * 128 + lane], sn = fc[s * 128 + 64 + lane];
    size_t ob = ((size_t)((b * 4 + kv) * 2048) + s) * 128;
    Kb[ob + lane]      = __float2bfloat16(n1 * cs - n2 * sn);
    Kb[ob + 64 + lane] = __float2bfloat16(n2 * cs + n1 * sn);
  } else {
    // ---- V transpose: 64x64 tile via padded LDS ----
    __shared__ __hip_bfloat16 tile[64][65];
    const int t = bid - 20480;                // 512 tiles = 32 x 2 x 8
    const int s0 = (t & 31) * 64, d0 = ((t >> 5) & 1) * 64, bk = t >> 6;
    const int b = bk >> 2, kv = bk & 3;
    const int tid = threadIdx.x;
#pragma unroll
    for (int i = 0; i < 16; ++i) {
      int e = i * 256 + tid;
      int rr2 = e >> 6, c = e & 63;  // rr2 = s-idx, c = d-idx
      tile[rr2][c] = qkv[(size_t)(b * 2048 + s0 + rr2) * 5120 + 4608 + kv * 128 + d0 + c];
    }
    __syncthreads();
#pragma unroll
    for (int i = 0; i < 16; ++i) {
      int e = i * 256 + tid;
      int rr2 = e >> 6, c = e & 63;  // rr2 = d-idx, c = s-idx
      vt[(size_t)(bk * 128 + d0 + rr2) * 2048 + s0 + c] = tile[c][rr2];
    }
  }
}

// ---------------- causal GQA flash attention + sigmoid gate ----------------
// 512 blocks (2/CU) x 512 threads = 8 waves; DYNAMIC work-stealing via a
// device-scope atomic counter, tasks sorted LONGEST-FIRST (LPT): task i ->
// qt2 = 15 - (i>>5), hb = i&31. Each task = one 128-q-row tile; blocks loop
// grabbing tasks so CUs equalize (~34 tile-units each, 16 waves resident).
// Inner body: SWAPPED QK^T in-register softmax, T2 swizzle, T5 setprio,
// T13 defer-max, wave-uniform causal-mask skip.
__global__ __launch_bounds__(512) void flash_attn(const __hip_bfloat16* __restrict__ Qb,
                                                  const __hip_bfloat16* __restrict__ Kb,
                                                  const __hip_bfloat16* __restrict__ Vt,
                                                  const __hip_bfloat16* __restrict__ qkv,
                                                  __hip_bfloat16* __restrict__ attn_g,
                                                  int* __restrict__ cnt) {
  const int tid = threadIdx.x, wave = tid >> 6, lane = tid & 63;
  const int lr = lane & 15, lg = lane >> 4;

  __shared__ __attribute__((aligned(16))) __hip_bfloat16 Ks[64 * 128];   // swz256
  __shared__ __attribute__((aligned(16))) __hip_bfloat16 Vs[128 * 64];   // swz128
  __shared__ __attribute__((aligned(16))) __hip_bfloat16 Ps[8][16 * 64]; // per-wave
  __shared__ int sh_task;

  char* PsW = (char*)&Ps[0][0] + wave * 2048;
  const float sc = 0.08838834764831845f;  // 1/sqrt(128)

  while (true) {
    if (tid == 0) sh_task = atomicAdd(cnt, 1);
    __syncthreads();
    const int task = sh_task;          // uniform across block
    if (task >= 512) break;

    const int qt2 = 15 - (task >> 5);  // longest-first (LPT)
    const int hb = task & 31;
    const int h = hb & 15, b = hb >> 4;
    const int kvh = h >> 2;

    bfrag qf[4];
    {
      const __hip_bfloat16* Qp =
          Qb + ((size_t)((b * 16 + h) * 2048) + qt2 * 128 + wave * 16 + lr) * 128;
#pragma unroll
      for (int kk = 0; kk < 4; ++kk) qf[kk] = *(const bfrag*)(Qp + kk * 32 + lg * 8);
    }

    facc o[8];
#pragma unroll
    for (int i = 0; i < 8; ++i) o[i] = (facc){0.f, 0.f, 0.f, 0.f};
    float m_s = -INFINITY;  // running max for q-row (lane&15)
    float l_s = 0.f;        // running denom for q-row (lane&15)

    const char* Kg0 = (const char*)(Kb + (size_t)((b * 4 + kvh) * 2048) * 128);
    const char* Vg0 = (const char*)(Vt + (size_t)((b * 4 + kvh) * 128) * 2048);

    const int T = 2 * qt2 + 2;
    for (int t = 0; t < T; ++t) {
      // stage K tile (64x128, 16KB) + Vt tile across 8 waves (2 segs/wave),
      // pre-swizzling the GLOBAL source so swizzled reads see correct data.
#pragma unroll
      for (int i = 0; i < 2; ++i) {
        const int wb = i * 8192 + wave * 1024;
        const int bo = wb + lane * 16;
        gl_lds16(Kg0 + (size_t)t * 16384 + swz256(bo), (char*)Ks + wb);
        const int sa = swz128(bo);
        gl_lds16(Vg0 + (size_t)(bo >> 7) * 4096 + (size_t)t * 128 + (sa & 127),
                 (char*)Vs + wb);
      }
      __syncthreads();

      // scores (swapped): st[n][r2] = S[kv = n*16+lg*4+r2][q = lr]
      facc st[4];
      __builtin_amdgcn_s_setprio(1);
#pragma unroll
      for (int n = 0; n < 4; ++n) {
        facc a = (facc){0.f, 0.f, 0.f, 0.f};
#pragma unroll
        for (int kk = 0; kk < 4; ++kk) {
          bfrag kf = *(const bfrag*)((const char*)Ks +
                         (((n * 16 + lr) * 256 + kk * 64 + lg * 16) ^ ((lr & 7) << 4)));
          a = mfma16(kf, qf[kk], a);   // SWAPPED: K as A, Q as B
        }
        st[n] = a;
      }
      __builtin_amdgcn_s_setprio(0);

      float pm = -INFINITY;
      if (t * 64 + 63 > qt2 * 128 + wave * 16) {   // wave-uniform: mask needed
        const int q_rel = qt2 * 128 + wave * 16 + lr - t * 64;
#pragma unroll
        for (int n = 0; n < 4; ++n)
#pragma unroll
          for (int r2 = 0; r2 < 4; ++r2) {
            float v = st[n][r2] * sc;
            if (n * 16 + lg * 4 + r2 > q_rel) v = -INFINITY;
            st[n][r2] = v;
            pm = fmaxf(pm, v);
          }
      } else {                                      // interior tile: no masking
#pragma unroll
        for (int n = 0; n < 4; ++n)
#pragma unroll
          for (int r2 = 0; r2 < 4; ++r2) {
            float v = st[n][r2] * sc;
            st[n][r2] = v;
            pm = fmaxf(pm, v);
          }
      }
      // cross-lane max over the 4 lanes holding this q-row (lg direction)
      pm = fmaxf(pm, __shfl_xor(pm, 16));
      pm = fmaxf(pm, __shfl_xor(pm, 32));

      // T13 defer-max: skip rescale when max growth <= 8 (first tile: m_s=-inf
      // -> no skip, so m_s becomes finite immediately).
      const bool skip = __all(pm <= m_s + 8.0f);
      float alpha = 1.0f;
      if (!skip) {
        float mn = fmaxf(m_s, pm);
        alpha = __expf(m_s - mn);
        m_s = mn;
      }

      float lsum = 0.f;
      us4 pw[4];
#pragma unroll
      for (int n = 0; n < 4; ++n)
#pragma unroll
        for (int r2 = 0; r2 < 4; ++r2) {
          float p = __expf(st[n][r2] - m_s);   // bounded by e^8 when deferred
          lsum += p;
          pw[n][r2] = f2bu(p);
        }
      lsum += __shfl_xor(lsum, 16);
      lsum += __shfl_xor(lsum, 32);
      l_s = l_s * alpha + lsum;

      // P write: 4 consecutive kv per lane per n-tile -> ds_write_b64
#pragma unroll
      for (int n = 0; n < 4; ++n) {
        const int byte = lr * 128 + n * 32 + lg * 8;
        *(us4*)(PsW + (byte ^ ((lr & 7) << 4))) = pw[n];
      }

      // rescale O only when max moved (acc layout rows q = lg*4+r2)
      if (!skip) {
        float alpha_acc[4];
#pragma unroll
        for (int r2 = 0; r2 < 4; ++r2) alpha_acc[r2] = __shfl(alpha, lg * 4 + r2);
#pragma unroll
        for (int nn = 0; nn < 8; ++nn)
#pragma unroll
          for (int r2 = 0; r2 < 4; ++r2) o[nn][r2] *= alpha_acc[r2];
      }

      // O += P (16x64) @ V (64x128)   (compiler inserts the Ps RAW lgkmcnt)
      __builtin_amdgcn_s_setprio(1);
#pragma unroll
      for (int kk2 = 0; kk2 < 2; ++kk2) {
        bfrag pa = *(const bfrag*)((const char*)PsW +
                       ((lr * 128 + kk2 * 64 + lg * 16) ^ ((lr & 7) << 4)));
#pragma unroll
        for (int nn = 0; nn < 8; ++nn) {
          bfrag vb = *(const bfrag*)((const char*)Vs +
                         (((nn * 16 + lr) * 128 + kk2 * 64 + lg * 16) ^ ((lr & 7) << 4)));
          o[nn] = mfma16(pa, vb, o[nn]);
        }
      }
      __builtin_amdgcn_s_setprio(0);
      __syncthreads();  // before next tile's staging overwrites Ks/Vs
    }

    // epilogue: normalize, sigmoid-gate, store bf16 [b*S+q][h*128+d]
    float inv = 1.0f / l_s;             // stat layout (q = lr)
    float inv_acc[4];
#pragma unroll
    for (int r2 = 0; r2 < 4; ++r2) inv_acc[r2] = __shfl(inv, lg * 4 + r2);
    const int q_base = qt2 * 128 + wave * 16 + lg * 4;
#pragma unroll
    for (int r2 = 0; r2 < 4; ++r2) {
      int q = q_base + r2;
      const __hip_bfloat16* gp = qkv + (size_t)(b * 2048 + q) * 5120 + h * 256 + 128;
      __hip_bfloat16* op = attn_g + (size_t)(b * 2048 + q) * 2048 + h * 128;
#pragma unroll
      for (int nn = 0; nn < 8; ++nn) {
        int d = nn * 16 + lr;
        float g = __bfloat162float(gp[d]);
        float sig = 1.0f / (1.0f + __expf(-g));
        op[d] = __float2bfloat16(o[nn][r2] * inv_acc[r2] * sig);
      }
    }
  }
}

// ---------------- launch ----------------
extern "C" void kernel_launch(void* const* d_in, const int* in_sizes, int n_in,
                              void* d_out, int out_size, void* d_ws, size_t ws_size,
                              hipStream_t stream) {
  (void)in_sizes; (void)n_in; (void)out_size; (void)ws_size;
  const float* x  = (const float*)d_in[0];
  const float* fc = (const float*)d_in[1];
  const float* Wq = (const float*)d_in[2];
  const float* Wk = (const float*)d_in[3];
  const float* Wv = (const float*)d_in[4];
  const float* Wo = (const float*)d_in[5];
  const float* qw = (const float*)d_in[6];
  const float* kw = (const float*)d_in[7];
  float* out = (float*)d_out;
  char* ws = (char*)d_ws;

  // workspace layout (bytes), total 92,274,688
  auto* x_bf   = (__hip_bfloat16*)(ws + 0);          // 16,777,216  [4096][2048]
  auto* wqkv   = (__hip_bfloat16*)(ws + 16777216);   // 20,971,520  [5120][2048]
  auto* wo_bf  = (__hip_bfloat16*)(ws + 37748736);   //  8,388,608  [2048][2048]
  auto* qkvraw = (__hip_bfloat16*)(ws + 46137344);   // 41,943,040  [4096][5120]
  auto* vt     = (__hip_bfloat16*)(ws + 88080384);   //  4,194,304  [b][kv][128][2048]
  auto* attn_g = x_bf;                               // alias: x_bf dead after QKV GEMM
  auto* Qb     = wqkv;                               // alias: weights dead after GEMM
  auto* Kb     = (__hip_bfloat16*)(ws + 33554432);   //  4,194,304 (tail of wqkv region)
  // task counter: first element of qkvraw's v-slice (row 0, col 4608) —
  // written by QKV GEMM, consumed by fused_prep's vtrans, DEAD during flash.
  int* cnt = (int*)(ws + 46137344 + 4608 * 2);

  // fused cast of all five f32 tensors to bf16 (one dispatch)
  cast_all<<<2048, 256, 0, stream>>>(x, Wq, Wk, Wv, Wo,
                                     (unsigned short*)x_bf,
                                     (unsigned short*)wqkv,
                                     (unsigned short*)wo_bf);

  // QKV projection: [4096][5120] = x_bf @ wqkv^T  (XCD rects: 4 x-rects of 10x16)
  gemm_bt<__hip_bfloat16><<<dim3(40, 32), 256, 0, stream>>>(x_bf, wqkv, qkvraw,
                                                            4096, 5120, 2048, 4);

  // fused q-norm/rope + k-norm/rope + V-transpose (one dispatch)
  fused_prep<<<20992, 256, 0, stream>>>(qkvraw, qw, kw, fc, Qb, Kb, vt);

  // reset the work-stealing counter (graph-capture-safe async memset)
  hipMemsetAsync(cnt, 0, 4, stream);

  flash_attn<<<512, 512, 0, stream>>>(Qb, Kb, vt, qkvraw, attn_g, cnt);

  // output projection: d_out[4096][2048] = attn_g @ wo_bf^T (XCD rects: 2 of 8x8)
  gemm_bt<float><<<dim3(16, 32), 256, 0, stream>>>(attn_g, wo_bf, out,
                                                   4096, 2048, 2048, 2);
}